// Round 15
// baseline (315.751 us; speedup 1.0000x reference)
//
#include <hip/hip_runtime.h>
#include <hip/hip_fp16.h>

// ---------------------------------------------------------------------------
// MSHGAT forward, round 15:
//  - tail: WL (weights) LDS staging dropped -> weights read broadcast from
//    L1 (16KB, resident). LDS 52.7->35.3KB -> 4 blocks/CU (was 3; R14
//    post-mortem: tail is occupancy-capped, not transcendental-capped).
//  - gathers: depth-2 software pipeline (2 independent row loads in flight
//    per subgroup). R10 fp16-neutral => latency-bound, not BW-bound.
//  - everything else unchanged from R14.
// N=50000, D=64, E=600000, NNZ=800000.
// ---------------------------------------------------------------------------

#define SEGSH 8      // seg = key >> 8 (256 keys per seg)
#define MAXSEG 256   // supports N <= 65536
#define PBLK 256     // partition blocks (p1/p3)

__device__ __forceinline__ float fast_tanh(float x) {
    float xc = fminf(fmaxf(x, -15.f), 15.f);
    float e = __expf(2.f * xc);
    return (e - 1.f) / (e + 1.f);
}

// ---- P1: per-block per-(stream,seg) counts ----------------------------------
__global__ __launch_bounds__(256) void p1_count_kernel(const int* __restrict__ dst, int e,
                                                       const int* __restrict__ row,
                                                       const int* __restrict__ col, int nnz,
                                                       int* __restrict__ blockcnt, int nseg) {
    __shared__ int lc[3 * MAXSEG];
    for (int i = threadIdx.x; i < 3 * nseg; i += 256) lc[i] = 0;
    __syncthreads();
    int ce = (e + PBLK - 1) / PBLK;
    int cz = (nnz + PBLK - 1) / PBLK;
    int e0 = blockIdx.x * ce, e1 = min(e0 + ce, e);
    for (int i = e0 + threadIdx.x; i < e1; i += 256)
        atomicAdd(&lc[dst[i] >> SEGSH], 1);
    int z0 = blockIdx.x * cz, z1 = min(z0 + cz, nnz);
    for (int i = z0 + threadIdx.x; i < z1; i += 256) {
        atomicAdd(&lc[nseg + (col[i] >> SEGSH)], 1);
        atomicAdd(&lc[2 * nseg + (row[i] >> SEGSH)], 1);
    }
    __syncthreads();
    for (int r = threadIdx.x; r < 3 * nseg; r += 256)
        blockcnt[r * PBLK + blockIdx.x] = lc[r];
}

// ---- P2a: per-row (stream,seg) exclusive scan over the PBLK block counts ----
__global__ __launch_bounds__(256) void p2a_kernel(int* __restrict__ blockcnt,
                                                  int* __restrict__ segtot, int rows) {
    int rw = blockIdx.x * 4 + (threadIdx.x >> 6);
    if (rw >= rows) return;
    int ln = threadIdx.x & 63;
    int b = rw * PBLK + ln * 4;
    int v0 = blockcnt[b], v1 = blockcnt[b + 1], v2 = blockcnt[b + 2], v3 = blockcnt[b + 3];
    int s = v0 + v1 + v2 + v3;
    int incl = s;
    for (int d = 1; d < 64; d <<= 1) {
        int t = __shfl_up(incl, d, 64);
        if (ln >= d) incl += t;
    }
    int excl = incl - s;
    blockcnt[b]     = excl;
    blockcnt[b + 1] = excl + v0;
    blockcnt[b + 2] = excl + v0 + v1;
    blockcnt[b + 3] = excl + v0 + v1 + v2;
    if (ln == 63) segtot[rw] = incl;
}

// ---- P2b: per-stream exclusive scan over seg totals -> segoff ---------------
__global__ __launch_bounds__(192) void p2b_kernel(const int* __restrict__ segtot,
                                                  int* __restrict__ segoff, int nseg) {
    int st = threadIdx.x >> 6, ln = threadIdx.x & 63;
    int chunk = (nseg + 63) / 64;
    int s0 = ln * chunk, s1 = min(s0 + chunk, nseg);
    int sum = 0;
    for (int i = s0; i < s1; ++i) sum += segtot[st * nseg + i];
    int incl = sum;
    for (int d = 1; d < 64; d <<= 1) {
        int v = __shfl_up(incl, d, 64);
        if (ln >= d) incl += v;
    }
    int run = incl - sum;
    for (int i = s0; i < s1; ++i) {
        segoff[st * nseg + i] = run;
        run += segtot[st * nseg + i];
    }
}

// ---- P3: scatter entries into per-seg runs (pre-scanned bases) --------------
__global__ __launch_bounds__(256) void p3_scatter_kernel(const int* __restrict__ src,
                                                         const int* __restrict__ dst, int e,
                                                         const int* __restrict__ row,
                                                         const int* __restrict__ col,
                                                         const float* __restrict__ val, int nnz,
                                                         const int* __restrict__ blockcnt,
                                                         const int* __restrict__ segoff,
                                                         unsigned* __restrict__ runG,
                                                         uint2* __restrict__ runC,
                                                         uint2* __restrict__ runR, int nseg) {
    __shared__ int base[3 * MAXSEG];
    __shared__ int cnt[3 * MAXSEG];
    for (int i = threadIdx.x; i < 3 * nseg; i += 256) {
        base[i] = segoff[i] + blockcnt[i * PBLK + blockIdx.x];
        cnt[i] = 0;
    }
    __syncthreads();
    int ce = (e + PBLK - 1) / PBLK;
    int cz = (nnz + PBLK - 1) / PBLK;
    int e0 = blockIdx.x * ce, e1 = min(e0 + ce, e);
    for (int i = e0 + threadIdx.x; i < e1; i += 256) {
        int d = dst[i];
        int sg = d >> SEGSH;
        int p = atomicAdd(&cnt[sg], 1);
        runG[base[sg] + p] = ((unsigned)d << 16) | (unsigned)src[i];
    }
    int z0 = blockIdx.x * cz, z1 = min(z0 + cz, nnz);
    for (int i = z0 + threadIdx.x; i < z1; i += 256) {
        int r = row[i], c = col[i];
        unsigned hv = (unsigned)__half_as_ushort(__float2half(val[i]));
        int sgc = nseg + (c >> SEGSH);
        int p = atomicAdd(&cnt[sgc], 1);
        runC[base[sgc] + p] = make_uint2((unsigned)c, ((unsigned)r << 16) | hv);
        int sgr = 2 * nseg + (r >> SEGSH);
        p = atomicAdd(&cnt[sgr], 1);
        runR[base[sgr] + p] = make_uint2((unsigned)r, ((unsigned)c << 16) | hv);
    }
}

// ---- CSR build: one block per seg. count -> scan (off, dinv) -> scatter -----
__global__ __launch_bounds__(256) void csr_build_kernel(const unsigned* __restrict__ runG,
                                                        const uint2* __restrict__ runC,
                                                        const uint2* __restrict__ runR,
                                                        const int* __restrict__ segoff,
                                                        const int* __restrict__ segtot,
                                                        int nseg, int n,
                                                        int* __restrict__ gcn_off,
                                                        int* __restrict__ hgc_off,
                                                        int* __restrict__ hgr_off,
                                                        float* __restrict__ dinv,
                                                        unsigned short* __restrict__ gsrcs,
                                                        unsigned* __restrict__ entc,
                                                        unsigned* __restrict__ entr) {
    __shared__ int cG[256], cC[256], cR[256];
    int s = blockIdx.x;
    int t = threadIdx.x;
    cG[t] = 0; cC[t] = 0; cR[t] = 0;
    __syncthreads();
    int oG = segoff[s],            nG = segtot[s];
    int oC = segoff[nseg + s],     nC = segtot[nseg + s];
    int oR = segoff[2 * nseg + s], nR = segtot[2 * nseg + s];
    for (int i = t; i < nG; i += 256) atomicAdd(&cG[(runG[oG + i] >> 16) & 255], 1);
    for (int i = t; i < nC; i += 256) atomicAdd(&cC[runC[oC + i].x & 255], 1);
    for (int i = t; i < nR; i += 256) atomicAdd(&cR[runR[oR + i].x & 255], 1);
    __syncthreads();
    int vG = cG[t], vC = cC[t], vR = cR[t];
    for (int d = 1; d < 256; d <<= 1) {
        int tG = (t >= d) ? cG[t - d] : 0;
        int tC = (t >= d) ? cC[t - d] : 0;
        int tR = (t >= d) ? cR[t - d] : 0;
        __syncthreads();
        cG[t] += tG; cC[t] += tC; cR[t] += tR;
        __syncthreads();
    }
    int eG = cG[t] - vG, eC = cC[t] - vC, eR = cR[t] - vR;
    int key = (s << SEGSH) + t;
    if (key < n) {
        gcn_off[key] = oG + eG;
        hgc_off[key] = oC + eC;
        hgr_off[key] = oR + eR;
        dinv[key] = rsqrtf((float)(vG + 1));
    }
    if (key == n) {
        gcn_off[n] = oG + eG;
        hgc_off[n] = oC + eC;
        hgr_off[n] = oR + eR;
    }
    if (s == nseg - 1 && t == 255 && ((n & 255) == 0)) {
        gcn_off[n] = oG + cG[255];
        hgc_off[n] = oC + cC[255];
        hgr_off[n] = oR + cR[255];
    }
    __syncthreads();
    cG[t] = oG + eG; cC[t] = oC + eC; cR[t] = oR + eR;
    __syncthreads();
    for (int i = t; i < nG; i += 256) {
        unsigned u = runG[oG + i];
        int p = atomicAdd(&cG[(u >> 16) & 255], 1);
        gsrcs[p] = (unsigned short)(u & 0xffffu);
    }
    for (int i = t; i < nC; i += 256) {
        uint2 u = runC[oC + i];
        int p = atomicAdd(&cC[u.x & 255], 1);
        entc[p] = u.y;
    }
    for (int i = t; i < nR; i += 256) {
        uint2 u = runR[oR + i];
        int p = atomicAdd(&cR[u.x & 255], 1);
        entr[p] = u.y;
    }
}

// ---- weight precompute: W12 = W1@W2 (64x64), bw = b1@W2 (64) ----------------
__global__ __launch_bounds__(64) void wprep_kernel(const float* __restrict__ W1,  // 64x128
                                                   const float* __restrict__ W2,  // 128x64
                                                   const float* __restrict__ b1,  // 128
                                                   float* __restrict__ W12,
                                                   float* __restrict__ bw) {
    int r = blockIdx.x;
    int c = threadIdx.x;
    const float* a = (r < 64) ? (W1 + r * 128) : b1;
    float acc = 0.f;
#pragma unroll 8
    for (int k = 0; k < 128; ++k) acc = fmaf(a[k], W2[k * 64 + c], acc);
    if (r < 64) W12[r * 64 + c] = acc;
    else bw[c] = acc;
}

// ---- GCN gather (normalized), depth-2 pipelined ------------------------------
template <bool SDI>
__global__ __launch_bounds__(256) void gcn_gather_kernel(const float* __restrict__ x,
                                                         const float* __restrict__ dinv,
                                                         const int* __restrict__ off,
                                                         const unsigned short* __restrict__ srcs,
                                                         float* __restrict__ out,
                                                         float* __restrict__ sdi, int n) {
    int node = blockIdx.x * 4 + (threadIdx.x >> 6);
    if (node >= n) return;
    int lane = threadIdx.x & 63;
    int sub = lane >> 4;
    int q = lane & 15;
    int e0 = off[node], e1 = off[node + 1];
    float4 acc = make_float4(0.f, 0.f, 0.f, 0.f);
    float dsum = 0.f;
    int e = e0 + sub;
    while (e + 4 < e1) {                 // two independent rows in flight
        int sa = srcs[e], sb = srcs[e + 4];
        float da = dinv[sa], db = dinv[sb];
        const float4 va = *(const float4*)(x + (long long)sa * 64 + q * 4);
        const float4 vb = *(const float4*)(x + (long long)sb * 64 + q * 4);
        acc.x = fmaf(da, va.x, fmaf(db, vb.x, acc.x));
        acc.y = fmaf(da, va.y, fmaf(db, vb.y, acc.y));
        acc.z = fmaf(da, va.z, fmaf(db, vb.z, acc.z));
        acc.w = fmaf(da, va.w, fmaf(db, vb.w, acc.w));
        dsum += da + db;
        e += 8;
    }
    if (e < e1) {
        int sa = srcs[e];
        float da = dinv[sa];
        const float4 va = *(const float4*)(x + (long long)sa * 64 + q * 4);
        acc.x = fmaf(da, va.x, acc.x);
        acc.y = fmaf(da, va.y, acc.y);
        acc.z = fmaf(da, va.z, acc.z);
        acc.w = fmaf(da, va.w, acc.w);
        dsum += da;
    }
    acc.x += __shfl_xor(acc.x, 16, 64); acc.x += __shfl_xor(acc.x, 32, 64);
    acc.y += __shfl_xor(acc.y, 16, 64); acc.y += __shfl_xor(acc.y, 32, 64);
    acc.z += __shfl_xor(acc.z, 16, 64); acc.z += __shfl_xor(acc.z, 32, 64);
    acc.w += __shfl_xor(acc.w, 16, 64); acc.w += __shfl_xor(acc.w, 32, 64);
    if (SDI) { dsum += __shfl_xor(dsum, 16, 64); dsum += __shfl_xor(dsum, 32, 64); }
    if (sub == 0) {
        float dt = dinv[node];
        const float4 xs = *(const float4*)(x + (long long)node * 64 + q * 4);
        float4 o;
        o.x = dt * fmaf(dt, xs.x, acc.x);
        o.y = dt * fmaf(dt, xs.y, acc.y);
        o.z = dt * fmaf(dt, xs.z, acc.z);
        o.w = dt * fmaf(dt, xs.w, acc.w);
        *(float4*)(out + (long long)node * 64 + q * 4) = o;
        if (SDI && q == 0) sdi[node] = dt * (dt + dsum);
    }
}

// ---- GEMM h2 = u @ W12 + sdi[r]*bw + b2 : register-tiled, fused BN stats ----
#define GP 68
__global__ __launch_bounds__(256) void gemm_h2_kernel(const float* __restrict__ X,
                                                      const float* __restrict__ W12,
                                                      const float* __restrict__ bw,
                                                      const float* __restrict__ b2,
                                                      const float* __restrict__ sdi,
                                                      float* __restrict__ h2,
                                                      float* __restrict__ stats, int n) {
    __shared__ float Xs[64 * GP];   // X tile [row][k] ; reused for bn partials
    __shared__ float WL[64 * GP];   // W12 [k][m]
    __shared__ float cadd[64], b2l[64];
    int t = threadIdx.x;
    int tx = t & 15, ty = t >> 4;
    int r0 = blockIdx.x * 64;
    if (t < 64) cadd[t] = bw[t];
    else if (t < 128) b2l[t - 64] = b2[t - 64];
    for (int f = t; f < 1024; f += 256) {
        int d = f >> 4, k4 = (f & 15) << 2;
        *(float4*)&WL[d * GP + k4] = *(const float4*)&W12[d * 64 + k4];
        int gr = r0 + d;
        float4 xv = make_float4(0.f, 0.f, 0.f, 0.f);
        if (gr < n) xv = *(const float4*)&X[(long long)gr * 64 + k4];
        *(float4*)&Xs[d * GP + k4] = xv;
    }
    __syncthreads();

    float4 acc[4];
#pragma unroll
    for (int ri = 0; ri < 4; ++ri) acc[ri] = make_float4(0.f, 0.f, 0.f, 0.f);
    for (int k = 0; k < 64; k += 4) {
        float4 w0 = *(float4*)&WL[(k + 0) * GP + 4 * tx];
        float4 w1 = *(float4*)&WL[(k + 1) * GP + 4 * tx];
        float4 w2v = *(float4*)&WL[(k + 2) * GP + 4 * tx];
        float4 w3 = *(float4*)&WL[(k + 3) * GP + 4 * tx];
#pragma unroll
        for (int ri = 0; ri < 4; ++ri) {
            float4 xv = *(float4*)&Xs[(4 * ty + ri) * GP + k];
            acc[ri].x = fmaf(xv.x, w0.x, fmaf(xv.y, w1.x, fmaf(xv.z, w2v.x, fmaf(xv.w, w3.x, acc[ri].x))));
            acc[ri].y = fmaf(xv.x, w0.y, fmaf(xv.y, w1.y, fmaf(xv.z, w2v.y, fmaf(xv.w, w3.y, acc[ri].y))));
            acc[ri].z = fmaf(xv.x, w0.z, fmaf(xv.y, w1.z, fmaf(xv.z, w2v.z, fmaf(xv.w, w3.z, acc[ri].z))));
            acc[ri].w = fmaf(xv.x, w0.w, fmaf(xv.y, w1.w, fmaf(xv.z, w2v.w, fmaf(xv.w, w3.w, acc[ri].w))));
        }
    }

    float ps[4] = {0.f, 0.f, 0.f, 0.f}, pq[4] = {0.f, 0.f, 0.f, 0.f};
    float ca[4] = {cadd[4 * tx], cadd[4 * tx + 1], cadd[4 * tx + 2], cadd[4 * tx + 3]};
    float bb[4] = {b2l[4 * tx], b2l[4 * tx + 1], b2l[4 * tx + 2], b2l[4 * tx + 3]};
#pragma unroll
    for (int ri = 0; ri < 4; ++ri) {
        int r = r0 + 4 * ty + ri;
        if (r < n) {
            float sd = sdi[r];
            float4 v;
            v.x = acc[ri].x + sd * ca[0] + bb[0];
            v.y = acc[ri].y + sd * ca[1] + bb[1];
            v.z = acc[ri].z + sd * ca[2] + bb[2];
            v.w = acc[ri].w + sd * ca[3] + bb[3];
            *(float4*)&h2[(long long)r * 64 + 4 * tx] = v;
            ps[0] += v.x; ps[1] += v.y; ps[2] += v.z; ps[3] += v.w;
            pq[0] += v.x * v.x; pq[1] += v.y * v.y; pq[2] += v.z * v.z; pq[3] += v.w * v.w;
        }
    }
    __syncthreads();
    float* lsum = Xs;
    float* lsq  = Xs + 1024;
#pragma unroll
    for (int di = 0; di < 4; ++di) {
        lsum[ty * 64 + 4 * tx + di] = ps[di];
        lsq[ty * 64 + 4 * tx + di]  = pq[di];
    }
    __syncthreads();
    if (t < 64) {
        float s = 0.f, s2 = 0.f;
#pragma unroll
        for (int g = 0; g < 16; ++g) {
            s += lsum[g * 64 + t];
            s2 += lsq[g * 64 + t];
        }
        atomicAdd(&stats[t], s);
        atomicAdd(&stats[64 + t], s2);
    }
}

// ---- HGNN gather, depth-2 pipelined; BN applies bn+relu+bias to rows --------
template <bool BN>
__global__ __launch_bounds__(256) void hg_gather_kernel(const float* __restrict__ in,
                                                        const int* __restrict__ off,
                                                        const unsigned* __restrict__ ents,
                                                        const float* __restrict__ stats,
                                                        const float* __restrict__ gamma,
                                                        const float* __restrict__ beta,
                                                        const float* __restrict__ hbias,
                                                        float invN,
                                                        float* __restrict__ out, int n) {
    int node = blockIdx.x * 4 + (threadIdx.x >> 6);
    if (node >= n) return;
    int lane = threadIdx.x & 63;
    int sub = lane >> 4;
    int q = lane & 15;
    float sc[4], sh[4], hb[4];
    if (BN) {
#pragma unroll
        for (int c = 0; c < 4; ++c) {
            int col = q * 4 + c;
            float mu = stats[col] * invN;
            float var = stats[64 + col] * invN - mu * mu;
            float s = gamma[col] * rsqrtf(var + 1e-5f);
            sc[c] = s; sh[c] = beta[col] - mu * s; hb[c] = hbias[col];
        }
    }
    int e0 = off[node], e1 = off[node + 1];
    float4 acc = make_float4(0.f, 0.f, 0.f, 0.f);
    int e = e0 + sub;
    while (e + 4 < e1) {
        unsigned ta = ents[e], tb = ents[e + 4];
        float va_ = __half2float(__ushort_as_half((unsigned short)(ta & 0xffffu)));
        float vb_ = __half2float(__ushort_as_half((unsigned short)(tb & 0xffffu)));
        float4 a4 = *(const float4*)(in + (long long)(ta >> 16) * 64 + q * 4);
        float4 b4 = *(const float4*)(in + (long long)(tb >> 16) * 64 + q * 4);
        if (BN) {
            a4.x = fmaxf(fmaf(a4.x, sc[0], sh[0]), 0.f) + hb[0];
            a4.y = fmaxf(fmaf(a4.y, sc[1], sh[1]), 0.f) + hb[1];
            a4.z = fmaxf(fmaf(a4.z, sc[2], sh[2]), 0.f) + hb[2];
            a4.w = fmaxf(fmaf(a4.w, sc[3], sh[3]), 0.f) + hb[3];
            b4.x = fmaxf(fmaf(b4.x, sc[0], sh[0]), 0.f) + hb[0];
            b4.y = fmaxf(fmaf(b4.y, sc[1], sh[1]), 0.f) + hb[1];
            b4.z = fmaxf(fmaf(b4.z, sc[2], sh[2]), 0.f) + hb[2];
            b4.w = fmaxf(fmaf(b4.w, sc[3], sh[3]), 0.f) + hb[3];
        }
        acc.x = fmaf(va_, a4.x, fmaf(vb_, b4.x, acc.x));
        acc.y = fmaf(va_, a4.y, fmaf(vb_, b4.y, acc.y));
        acc.z = fmaf(va_, a4.z, fmaf(vb_, b4.z, acc.z));
        acc.w = fmaf(va_, a4.w, fmaf(vb_, b4.w, acc.w));
        e += 8;
    }
    if (e < e1) {
        unsigned ta = ents[e];
        float va_ = __half2float(__ushort_as_half((unsigned short)(ta & 0xffffu)));
        float4 a4 = *(const float4*)(in + (long long)(ta >> 16) * 64 + q * 4);
        if (BN) {
            a4.x = fmaxf(fmaf(a4.x, sc[0], sh[0]), 0.f) + hb[0];
            a4.y = fmaxf(fmaf(a4.y, sc[1], sh[1]), 0.f) + hb[1];
            a4.z = fmaxf(fmaf(a4.z, sc[2], sh[2]), 0.f) + hb[2];
            a4.w = fmaxf(fmaf(a4.w, sc[3], sh[3]), 0.f) + hb[3];
        }
        acc.x = fmaf(va_, a4.x, acc.x);
        acc.y = fmaf(va_, a4.y, acc.y);
        acc.z = fmaf(va_, a4.z, acc.z);
        acc.w = fmaf(va_, a4.w, acc.w);
    }
    acc.x += __shfl_xor(acc.x, 16, 64); acc.x += __shfl_xor(acc.x, 32, 64);
    acc.y += __shfl_xor(acc.y, 16, 64); acc.y += __shfl_xor(acc.y, 32, 64);
    acc.z += __shfl_xor(acc.z, 16, 64); acc.z += __shfl_xor(acc.z, 32, 64);
    acc.w += __shfl_xor(acc.w, 16, 64); acc.w += __shfl_xor(acc.w, 32, 64);
    if (sub == 0) *(float4*)(out + (long long)node * 64 + q * 4) = acc;
}

// ---- fused tail: softmax -> fc1 -> fusion gate; weights from L1, H in LDS ---
#define TPAD 68
__device__ __forceinline__ float dot4(float4 a, float4 b) {
    return fmaf(a.x, b.x, fmaf(a.y, b.y, fmaf(a.z, b.z, a.w * b.w)));
}

__global__ __launch_bounds__(256) void tail_kernel(const float* __restrict__ x2,
                                                   const float* __restrict__ h2raw,
                                                   const float* __restrict__ fc1_W,
                                                   const float* __restrict__ fusW1,
                                                   const float* __restrict__ b1,
                                                   const float* __restrict__ w2,
                                                   const float* __restrict__ b2,
                                                   const float* __restrict__ stats,
                                                   const float* __restrict__ gamma,
                                                   const float* __restrict__ beta,
                                                   float invN,
                                                   float* __restrict__ out, int n) {
    __shared__ float A[64 * TPAD];    // P (softmax probs), later S (subn)
    __shared__ float Hs[64 * TPAD];   // hidden tile (bn applied)
    __shared__ float bsc[64], bsh[64];
    int t = threadIdx.x;
    int tx = t & 15, ty = t >> 4;
    int r0 = blockIdx.x * 64;

    if (t < 64) {
        float mu = stats[t] * invN;
        float var = stats[64 + t] * invN - mu * mu;
        float s = gamma[t] * rsqrtf(var + 1e-5f);
        bsc[t] = s; bsh[t] = beta[t] - mu * s;
    }
    __syncthreads();

    float b1d[4], w2d[4];
#pragma unroll
    for (int di = 0; di < 4; ++di) {
        b1d[di] = b1[tx + 16 * di];
        w2d[di] = w2[tx + 16 * di];
    }
    float b20 = b2[0];

    // bn(hidden) tile -> Hs (coalesced float4)
    for (int f = t; f < 1024; f += 256) {
        int d = f >> 4, k4 = (f & 15) << 2;
        int gr = r0 + d;
        float4 hv = make_float4(0.f, 0.f, 0.f, 0.f);
        if (gr < n) {
            hv = *(const float4*)&h2raw[(long long)gr * 64 + k4];
            hv.x = fmaf(hv.x, bsc[k4],     bsh[k4]);
            hv.y = fmaf(hv.y, bsc[k4 + 1], bsh[k4 + 1]);
            hv.z = fmaf(hv.z, bsc[k4 + 2], bsh[k4 + 2]);
            hv.w = fmaf(hv.w, bsc[k4 + 3], bsh[k4 + 3]);
        }
        *(float4*)&Hs[d * TPAD + k4] = hv;
    }

    // x2 tile: load + row softmax -> A
#pragma unroll
    for (int ri = 0; ri < 4; ++ri) {
        int rl = 4 * ty + ri;
        int r = r0 + rl;
        bool ok = r < n;
        float vv[4];
#pragma unroll
        for (int di = 0; di < 4; ++di)
            vv[di] = ok ? x2[(long long)r * 64 + tx + 16 * di] : 0.f;
        float m = fmaxf(fmaxf(vv[0], vv[1]), fmaxf(vv[2], vv[3]));
        for (int s = 1; s < 16; s <<= 1) m = fmaxf(m, __shfl_xor(m, s, 16));
        float e0 = __expf(vv[0] - m), e1 = __expf(vv[1] - m);
        float e2 = __expf(vv[2] - m), e3 = __expf(vv[3] - m);
        float sm = e0 + e1 + e2 + e3;
        for (int s = 1; s < 16; s <<= 1) sm += __shfl_xor(sm, s, 16);
        float inv = 1.0f / sm;
        A[rl * TPAD + tx]      = e0 * inv;
        A[rl * TPAD + tx + 16] = e1 * inv;
        A[rl * TPAD + tx + 32] = e2 * inv;
        A[rl * TPAD + tx + 48] = e3 * inv;
    }
    __syncthreads();

    // fc1: sn = P @ fc1_W^T  (weights broadcast-read from L1)
    float sn[4][4];
#pragma unroll
    for (int ri = 0; ri < 4; ++ri)
#pragma unroll
        for (int di = 0; di < 4; ++di) sn[ri][di] = 0.f;
    for (int k = 0; k < 64; k += 4) {
        float4 p4[4], w4[4];
#pragma unroll
        for (int ri = 0; ri < 4; ++ri) p4[ri] = *(float4*)&A[(4 * ty + ri) * TPAD + k];
#pragma unroll
        for (int di = 0; di < 4; ++di)
            w4[di] = *(const float4*)&fc1_W[(tx + 16 * di) * 64 + k];
#pragma unroll
        for (int ri = 0; ri < 4; ++ri)
#pragma unroll
            for (int di = 0; di < 4; ++di)
                sn[ri][di] += dot4(p4[ri], w4[di]);
    }
    __syncthreads();

    // S (subn) -> A
#pragma unroll
    for (int ri = 0; ri < 4; ++ri)
#pragma unroll
        for (int di = 0; di < 4; ++di)
            A[(4 * ty + ri) * TPAD + tx + 16 * di] = sn[ri][di];
    __syncthreads();

    // gates: aH/aS (fus weights broadcast-read from L1)
    float aH[4][4], aS[4][4];
#pragma unroll
    for (int ri = 0; ri < 4; ++ri)
#pragma unroll
        for (int di = 0; di < 4; ++di) { aH[ri][di] = b1d[di]; aS[ri][di] = b1d[di]; }
    for (int k = 0; k < 64; k += 4) {
        float4 h4[4], s4[4], w4[4];
#pragma unroll
        for (int ri = 0; ri < 4; ++ri) {
            h4[ri] = *(float4*)&Hs[(4 * ty + ri) * TPAD + k];
            s4[ri] = *(float4*)&A[(4 * ty + ri) * TPAD + k];
        }
#pragma unroll
        for (int di = 0; di < 4; ++di)
            w4[di] = *(const float4*)&fusW1[(tx + 16 * di) * 64 + k];
#pragma unroll
        for (int ri = 0; ri < 4; ++ri)
#pragma unroll
            for (int di = 0; di < 4; ++di) {
                aH[ri][di] += dot4(h4[ri], w4[di]);
                aS[ri][di] += dot4(s4[ri], w4[di]);
            }
    }

#pragma unroll
    for (int ri = 0; ri < 4; ++ri) {
        int rl = 4 * ty + ri;
        int r = r0 + rl;
        float pH = 0.f, pS = 0.f;
#pragma unroll
        for (int di = 0; di < 4; ++di) {
            pH = fmaf(fast_tanh(aH[ri][di]), w2d[di], pH);
            pS = fmaf(fast_tanh(aS[ri][di]), w2d[di], pS);
        }
        for (int s = 1; s < 16; s <<= 1) {
            pH += __shfl_xor(pH, s, 16);
            pS += __shfl_xor(pS, s, 16);
        }
        pH += b20; pS += b20;
        float mx = fmaxf(pH, pS);
        float eH = __expf(pH - mx), eS = __expf(pS - mx);
        float inv = 1.0f / (eH + eS);
        if (r < n) {
#pragma unroll
            for (int di = 0; di < 4; ++di) {
                int d = tx + 16 * di;
                float hv = Hs[rl * TPAD + d];
                out[(long long)r * 64 + d] = (eH * hv + eS * sn[ri][di]) * inv;
            }
        }
    }
}

// ---------------------------------------------------------------------------
extern "C" void kernel_launch(void* const* d_in, const int* in_sizes, int n_in,
                              void* d_out, int out_size, void* d_ws, size_t ws_size,
                              hipStream_t stream) {
    const float* emb       = (const float*)d_in[0];
    const float* W1        = (const float*)d_in[1];
    const float* b1        = (const float*)d_in[2];
    const float* W2        = (const float*)d_in[3];
    const float* b2        = (const float*)d_in[4];
    const float* gamma     = (const float*)d_in[5];
    const float* beta      = (const float*)d_in[6];
    const float* hgc1_bias = (const float*)d_in[7];
    const float* fc1_W     = (const float*)d_in[8];
    const float* fus_l1_W  = (const float*)d_in[9];
    const float* fus_l1_b  = (const float*)d_in[10];
    const float* fus_l2_W  = (const float*)d_in[11];
    const float* fus_l2_b  = (const float*)d_in[12];
    const float* hg_val    = (const float*)d_in[13];
    const int*   edge_index= (const int*)d_in[14];
    const int*   hg_row    = (const int*)d_in[15];
    const int*   hg_col    = (const int*)d_in[16];

    const int N    = in_sizes[0] / 64;
    const int E    = in_sizes[14] / 2;
    const int NNZ  = in_sizes[13];
    const int Np   = (N + 3) & ~3;
    const int NSEG = (N + 255) >> 8;
    const int* src = edge_index;
    const int* dst = edge_index + E;

    float* ws      = (float*)d_ws;
    float* dinv    = ws;
    float* sdi     = dinv + Np;
    float* w12     = sdi + Np;
    float* bw      = w12 + 4096;
    float* stats   = bw + 64;
    int*   gcn_off = (int*)(stats + 128);
    int*   hgc_off = gcn_off + (Np + 4);
    int*   hgr_off = hgc_off + (Np + 4);
    int*   segtot  = hgr_off + (Np + 4);
    int*   segoff  = segtot + 3 * NSEG;
    int*   blockcnt= segoff + 3 * NSEG;
    unsigned short* gcn_srcs = (unsigned short*)(blockcnt + 3 * NSEG * PBLK);
    unsigned* hgc_ent = (unsigned*)(gcn_srcs + ((E + 1) & ~1));
    unsigned* hgr_ent = hgc_ent + NNZ;
    float* buf1    = (float*)(hgr_ent + NNZ);
    float* buf2    = buf1 + (size_t)128 * Np;

    const int Ep = (E + 1) & ~1;
    unsigned* runG = (unsigned*)buf1;
    uint2*    runC = (uint2*)(runG + Ep);
    uint2*    runR = runC + NNZ;

    float* tbuf = buf2;                      // A-hat emb        N x 64
    float* ubuf = buf1;                      // A-hat^2 emb      N x 64
    float* h2   = buf1 + (size_t)64 * Np;    // raw h2 (pre-bn)  N x 64
    float* eemb = buf2;                      // edge emb         N x 64 (tbuf dead)
    float* x2   = buf1;                      // HGNN out         N x 64 (ubuf dead)
    float* out  = (float*)d_out;

    const float invN = 1.0f / (float)N;

    // --- CSR build: count -> scans -> scatter runs -> per-seg csr_build ---
    hipMemsetAsync(stats, 0, 128 * sizeof(float), stream);
    p1_count_kernel<<<PBLK, 256, 0, stream>>>(dst, E, hg_row, hg_col, NNZ, blockcnt, NSEG);
    p2a_kernel<<<(3 * NSEG + 3) / 4, 256, 0, stream>>>(blockcnt, segtot, 3 * NSEG);
    p2b_kernel<<<1, 192, 0, stream>>>(segtot, segoff, NSEG);
    p3_scatter_kernel<<<PBLK, 256, 0, stream>>>(src, dst, E, hg_row, hg_col, hg_val, NNZ,
                                                blockcnt, segoff, runG, runC, runR, NSEG);
    csr_build_kernel<<<NSEG, 256, 0, stream>>>(runG, runC, runR, segoff, segtot, NSEG, N,
                                               gcn_off, hgc_off, hgr_off, dinv,
                                               gcn_srcs, hgc_ent, hgr_ent);

    // --- weight precompute + reassociated GCN ---
    wprep_kernel<<<65, 64, 0, stream>>>(W1, W2, b1, w12, bw);
    gcn_gather_kernel<true><<<(N + 3) / 4, 256, 0, stream>>>(emb, dinv, gcn_off, gcn_srcs,
                                                             tbuf, sdi, N);
    gcn_gather_kernel<false><<<(N + 3) / 4, 256, 0, stream>>>(tbuf, dinv, gcn_off, gcn_srcs,
                                                              ubuf, nullptr, N);
    gemm_h2_kernel<<<(N + 63) / 64, 256, 0, stream>>>(ubuf, w12, bw, b2, sdi, h2, stats, N);

    // --- HGNN: edge_emb = G^T relu(bn(h2))+bias ; x2 = G edge_emb ---
    hg_gather_kernel<true><<<(N + 3) / 4, 256, 0, stream>>>(h2, hgc_off, hgc_ent,
                                                            stats, gamma, beta, hgc1_bias,
                                                            invN, eemb, N);
    hg_gather_kernel<false><<<(N + 3) / 4, 256, 0, stream>>>(eemb, hgr_off, hgr_ent,
                                                             nullptr, nullptr, nullptr, nullptr,
                                                             0.f, x2, N);

    // --- fused softmax + fc1 + fusion gate (bn on hidden inline) ---
    tail_kernel<<<(N + 63) / 64, 256, 0, stream>>>(x2, h2, fc1_W, fus_l1_W, fus_l1_b,
                                                   fus_l2_W, fus_l2_b, stats, gamma, beta,
                                                   invN, out, N);
}

// Round 16
// 279.042 us; speedup vs baseline: 1.1316x; 1.1316x over previous
//
#include <hip/hip_runtime.h>
#include <hip/hip_fp16.h>

// ---------------------------------------------------------------------------
// MSHGAT forward, round 16:
//  - tail: WL back in LDS (R15's L1 "broadcast" was 16-address scattered
//    loads -> 75us). Tile halved to 32 rows: grid 782->1563 blocks (tail was
//    GRID-limited at 3.05 blocks/CU), LDS 52.7->34.8KB -> 4 blocks/CU,
//    half the per-block latency.
//  - gathers keep depth-2 pipeline (R15: mild win).
// N=50000, D=64, E=600000, NNZ=800000.
// ---------------------------------------------------------------------------

#define SEGSH 8      // seg = key >> 8 (256 keys per seg)
#define MAXSEG 256   // supports N <= 65536
#define PBLK 256     // partition blocks (p1/p3)

__device__ __forceinline__ float fast_tanh(float x) {
    float xc = fminf(fmaxf(x, -15.f), 15.f);
    float e = __expf(2.f * xc);
    return (e - 1.f) / (e + 1.f);
}

// ---- P1: per-block per-(stream,seg) counts ----------------------------------
__global__ __launch_bounds__(256) void p1_count_kernel(const int* __restrict__ dst, int e,
                                                       const int* __restrict__ row,
                                                       const int* __restrict__ col, int nnz,
                                                       int* __restrict__ blockcnt, int nseg) {
    __shared__ int lc[3 * MAXSEG];
    for (int i = threadIdx.x; i < 3 * nseg; i += 256) lc[i] = 0;
    __syncthreads();
    int ce = (e + PBLK - 1) / PBLK;
    int cz = (nnz + PBLK - 1) / PBLK;
    int e0 = blockIdx.x * ce, e1 = min(e0 + ce, e);
    for (int i = e0 + threadIdx.x; i < e1; i += 256)
        atomicAdd(&lc[dst[i] >> SEGSH], 1);
    int z0 = blockIdx.x * cz, z1 = min(z0 + cz, nnz);
    for (int i = z0 + threadIdx.x; i < z1; i += 256) {
        atomicAdd(&lc[nseg + (col[i] >> SEGSH)], 1);
        atomicAdd(&lc[2 * nseg + (row[i] >> SEGSH)], 1);
    }
    __syncthreads();
    for (int r = threadIdx.x; r < 3 * nseg; r += 256)
        blockcnt[r * PBLK + blockIdx.x] = lc[r];
}

// ---- P2a: per-row (stream,seg) exclusive scan over the PBLK block counts ----
__global__ __launch_bounds__(256) void p2a_kernel(int* __restrict__ blockcnt,
                                                  int* __restrict__ segtot, int rows) {
    int rw = blockIdx.x * 4 + (threadIdx.x >> 6);
    if (rw >= rows) return;
    int ln = threadIdx.x & 63;
    int b = rw * PBLK + ln * 4;
    int v0 = blockcnt[b], v1 = blockcnt[b + 1], v2 = blockcnt[b + 2], v3 = blockcnt[b + 3];
    int s = v0 + v1 + v2 + v3;
    int incl = s;
    for (int d = 1; d < 64; d <<= 1) {
        int t = __shfl_up(incl, d, 64);
        if (ln >= d) incl += t;
    }
    int excl = incl - s;
    blockcnt[b]     = excl;
    blockcnt[b + 1] = excl + v0;
    blockcnt[b + 2] = excl + v0 + v1;
    blockcnt[b + 3] = excl + v0 + v1 + v2;
    if (ln == 63) segtot[rw] = incl;
}

// ---- P2b: per-stream exclusive scan over seg totals -> segoff ---------------
__global__ __launch_bounds__(192) void p2b_kernel(const int* __restrict__ segtot,
                                                  int* __restrict__ segoff, int nseg) {
    int st = threadIdx.x >> 6, ln = threadIdx.x & 63;
    int chunk = (nseg + 63) / 64;
    int s0 = ln * chunk, s1 = min(s0 + chunk, nseg);
    int sum = 0;
    for (int i = s0; i < s1; ++i) sum += segtot[st * nseg + i];
    int incl = sum;
    for (int d = 1; d < 64; d <<= 1) {
        int v = __shfl_up(incl, d, 64);
        if (ln >= d) incl += v;
    }
    int run = incl - sum;
    for (int i = s0; i < s1; ++i) {
        segoff[st * nseg + i] = run;
        run += segtot[st * nseg + i];
    }
}

// ---- P3: scatter entries into per-seg runs (pre-scanned bases) --------------
__global__ __launch_bounds__(256) void p3_scatter_kernel(const int* __restrict__ src,
                                                         const int* __restrict__ dst, int e,
                                                         const int* __restrict__ row,
                                                         const int* __restrict__ col,
                                                         const float* __restrict__ val, int nnz,
                                                         const int* __restrict__ blockcnt,
                                                         const int* __restrict__ segoff,
                                                         unsigned* __restrict__ runG,
                                                         uint2* __restrict__ runC,
                                                         uint2* __restrict__ runR, int nseg) {
    __shared__ int base[3 * MAXSEG];
    __shared__ int cnt[3 * MAXSEG];
    for (int i = threadIdx.x; i < 3 * nseg; i += 256) {
        base[i] = segoff[i] + blockcnt[i * PBLK + blockIdx.x];
        cnt[i] = 0;
    }
    __syncthreads();
    int ce = (e + PBLK - 1) / PBLK;
    int cz = (nnz + PBLK - 1) / PBLK;
    int e0 = blockIdx.x * ce, e1 = min(e0 + ce, e);
    for (int i = e0 + threadIdx.x; i < e1; i += 256) {
        int d = dst[i];
        int sg = d >> SEGSH;
        int p = atomicAdd(&cnt[sg], 1);
        runG[base[sg] + p] = ((unsigned)d << 16) | (unsigned)src[i];
    }
    int z0 = blockIdx.x * cz, z1 = min(z0 + cz, nnz);
    for (int i = z0 + threadIdx.x; i < z1; i += 256) {
        int r = row[i], c = col[i];
        unsigned hv = (unsigned)__half_as_ushort(__float2half(val[i]));
        int sgc = nseg + (c >> SEGSH);
        int p = atomicAdd(&cnt[sgc], 1);
        runC[base[sgc] + p] = make_uint2((unsigned)c, ((unsigned)r << 16) | hv);
        int sgr = 2 * nseg + (r >> SEGSH);
        p = atomicAdd(&cnt[sgr], 1);
        runR[base[sgr] + p] = make_uint2((unsigned)r, ((unsigned)c << 16) | hv);
    }
}

// ---- CSR build: one block per seg. count -> scan (off, dinv) -> scatter -----
__global__ __launch_bounds__(256) void csr_build_kernel(const unsigned* __restrict__ runG,
                                                        const uint2* __restrict__ runC,
                                                        const uint2* __restrict__ runR,
                                                        const int* __restrict__ segoff,
                                                        const int* __restrict__ segtot,
                                                        int nseg, int n,
                                                        int* __restrict__ gcn_off,
                                                        int* __restrict__ hgc_off,
                                                        int* __restrict__ hgr_off,
                                                        float* __restrict__ dinv,
                                                        unsigned short* __restrict__ gsrcs,
                                                        unsigned* __restrict__ entc,
                                                        unsigned* __restrict__ entr) {
    __shared__ int cG[256], cC[256], cR[256];
    int s = blockIdx.x;
    int t = threadIdx.x;
    cG[t] = 0; cC[t] = 0; cR[t] = 0;
    __syncthreads();
    int oG = segoff[s],            nG = segtot[s];
    int oC = segoff[nseg + s],     nC = segtot[nseg + s];
    int oR = segoff[2 * nseg + s], nR = segtot[2 * nseg + s];
    for (int i = t; i < nG; i += 256) atomicAdd(&cG[(runG[oG + i] >> 16) & 255], 1);
    for (int i = t; i < nC; i += 256) atomicAdd(&cC[runC[oC + i].x & 255], 1);
    for (int i = t; i < nR; i += 256) atomicAdd(&cR[runR[oR + i].x & 255], 1);
    __syncthreads();
    int vG = cG[t], vC = cC[t], vR = cR[t];
    for (int d = 1; d < 256; d <<= 1) {
        int tG = (t >= d) ? cG[t - d] : 0;
        int tC = (t >= d) ? cC[t - d] : 0;
        int tR = (t >= d) ? cR[t - d] : 0;
        __syncthreads();
        cG[t] += tG; cC[t] += tC; cR[t] += tR;
        __syncthreads();
    }
    int eG = cG[t] - vG, eC = cC[t] - vC, eR = cR[t] - vR;
    int key = (s << SEGSH) + t;
    if (key < n) {
        gcn_off[key] = oG + eG;
        hgc_off[key] = oC + eC;
        hgr_off[key] = oR + eR;
        dinv[key] = rsqrtf((float)(vG + 1));
    }
    if (key == n) {
        gcn_off[n] = oG + eG;
        hgc_off[n] = oC + eC;
        hgr_off[n] = oR + eR;
    }
    if (s == nseg - 1 && t == 255 && ((n & 255) == 0)) {
        gcn_off[n] = oG + cG[255];
        hgc_off[n] = oC + cC[255];
        hgr_off[n] = oR + cR[255];
    }
    __syncthreads();
    cG[t] = oG + eG; cC[t] = oC + eC; cR[t] = oR + eR;
    __syncthreads();
    for (int i = t; i < nG; i += 256) {
        unsigned u = runG[oG + i];
        int p = atomicAdd(&cG[(u >> 16) & 255], 1);
        gsrcs[p] = (unsigned short)(u & 0xffffu);
    }
    for (int i = t; i < nC; i += 256) {
        uint2 u = runC[oC + i];
        int p = atomicAdd(&cC[u.x & 255], 1);
        entc[p] = u.y;
    }
    for (int i = t; i < nR; i += 256) {
        uint2 u = runR[oR + i];
        int p = atomicAdd(&cR[u.x & 255], 1);
        entr[p] = u.y;
    }
}

// ---- weight precompute: W12 = W1@W2 (64x64), bw = b1@W2 (64) ----------------
__global__ __launch_bounds__(64) void wprep_kernel(const float* __restrict__ W1,  // 64x128
                                                   const float* __restrict__ W2,  // 128x64
                                                   const float* __restrict__ b1,  // 128
                                                   float* __restrict__ W12,
                                                   float* __restrict__ bw) {
    int r = blockIdx.x;
    int c = threadIdx.x;
    const float* a = (r < 64) ? (W1 + r * 128) : b1;
    float acc = 0.f;
#pragma unroll 8
    for (int k = 0; k < 128; ++k) acc = fmaf(a[k], W2[k * 64 + c], acc);
    if (r < 64) W12[r * 64 + c] = acc;
    else bw[c] = acc;
}

// ---- GCN gather (normalized), depth-2 pipelined ------------------------------
template <bool SDI>
__global__ __launch_bounds__(256) void gcn_gather_kernel(const float* __restrict__ x,
                                                         const float* __restrict__ dinv,
                                                         const int* __restrict__ off,
                                                         const unsigned short* __restrict__ srcs,
                                                         float* __restrict__ out,
                                                         float* __restrict__ sdi, int n) {
    int node = blockIdx.x * 4 + (threadIdx.x >> 6);
    if (node >= n) return;
    int lane = threadIdx.x & 63;
    int sub = lane >> 4;
    int q = lane & 15;
    int e0 = off[node], e1 = off[node + 1];
    float4 acc = make_float4(0.f, 0.f, 0.f, 0.f);
    float dsum = 0.f;
    int e = e0 + sub;
    while (e + 4 < e1) {
        int sa = srcs[e], sb = srcs[e + 4];
        float da = dinv[sa], db = dinv[sb];
        const float4 va = *(const float4*)(x + (long long)sa * 64 + q * 4);
        const float4 vb = *(const float4*)(x + (long long)sb * 64 + q * 4);
        acc.x = fmaf(da, va.x, fmaf(db, vb.x, acc.x));
        acc.y = fmaf(da, va.y, fmaf(db, vb.y, acc.y));
        acc.z = fmaf(da, va.z, fmaf(db, vb.z, acc.z));
        acc.w = fmaf(da, va.w, fmaf(db, vb.w, acc.w));
        dsum += da + db;
        e += 8;
    }
    if (e < e1) {
        int sa = srcs[e];
        float da = dinv[sa];
        const float4 va = *(const float4*)(x + (long long)sa * 64 + q * 4);
        acc.x = fmaf(da, va.x, acc.x);
        acc.y = fmaf(da, va.y, acc.y);
        acc.z = fmaf(da, va.z, acc.z);
        acc.w = fmaf(da, va.w, acc.w);
        dsum += da;
    }
    acc.x += __shfl_xor(acc.x, 16, 64); acc.x += __shfl_xor(acc.x, 32, 64);
    acc.y += __shfl_xor(acc.y, 16, 64); acc.y += __shfl_xor(acc.y, 32, 64);
    acc.z += __shfl_xor(acc.z, 16, 64); acc.z += __shfl_xor(acc.z, 32, 64);
    acc.w += __shfl_xor(acc.w, 16, 64); acc.w += __shfl_xor(acc.w, 32, 64);
    if (SDI) { dsum += __shfl_xor(dsum, 16, 64); dsum += __shfl_xor(dsum, 32, 64); }
    if (sub == 0) {
        float dt = dinv[node];
        const float4 xs = *(const float4*)(x + (long long)node * 64 + q * 4);
        float4 o;
        o.x = dt * fmaf(dt, xs.x, acc.x);
        o.y = dt * fmaf(dt, xs.y, acc.y);
        o.z = dt * fmaf(dt, xs.z, acc.z);
        o.w = dt * fmaf(dt, xs.w, acc.w);
        *(float4*)(out + (long long)node * 64 + q * 4) = o;
        if (SDI && q == 0) sdi[node] = dt * (dt + dsum);
    }
}

// ---- GEMM h2 = u @ W12 + sdi[r]*bw + b2 : register-tiled, fused BN stats ----
#define GP 68
__global__ __launch_bounds__(256) void gemm_h2_kernel(const float* __restrict__ X,
                                                      const float* __restrict__ W12,
                                                      const float* __restrict__ bw,
                                                      const float* __restrict__ b2,
                                                      const float* __restrict__ sdi,
                                                      float* __restrict__ h2,
                                                      float* __restrict__ stats, int n) {
    __shared__ float Xs[64 * GP];
    __shared__ float WL[64 * GP];
    __shared__ float cadd[64], b2l[64];
    int t = threadIdx.x;
    int tx = t & 15, ty = t >> 4;
    int r0 = blockIdx.x * 64;
    if (t < 64) cadd[t] = bw[t];
    else if (t < 128) b2l[t - 64] = b2[t - 64];
    for (int f = t; f < 1024; f += 256) {
        int d = f >> 4, k4 = (f & 15) << 2;
        *(float4*)&WL[d * GP + k4] = *(const float4*)&W12[d * 64 + k4];
        int gr = r0 + d;
        float4 xv = make_float4(0.f, 0.f, 0.f, 0.f);
        if (gr < n) xv = *(const float4*)&X[(long long)gr * 64 + k4];
        *(float4*)&Xs[d * GP + k4] = xv;
    }
    __syncthreads();

    float4 acc[4];
#pragma unroll
    for (int ri = 0; ri < 4; ++ri) acc[ri] = make_float4(0.f, 0.f, 0.f, 0.f);
    for (int k = 0; k < 64; k += 4) {
        float4 w0 = *(float4*)&WL[(k + 0) * GP + 4 * tx];
        float4 w1 = *(float4*)&WL[(k + 1) * GP + 4 * tx];
        float4 w2v = *(float4*)&WL[(k + 2) * GP + 4 * tx];
        float4 w3 = *(float4*)&WL[(k + 3) * GP + 4 * tx];
#pragma unroll
        for (int ri = 0; ri < 4; ++ri) {
            float4 xv = *(float4*)&Xs[(4 * ty + ri) * GP + k];
            acc[ri].x = fmaf(xv.x, w0.x, fmaf(xv.y, w1.x, fmaf(xv.z, w2v.x, fmaf(xv.w, w3.x, acc[ri].x))));
            acc[ri].y = fmaf(xv.x, w0.y, fmaf(xv.y, w1.y, fmaf(xv.z, w2v.y, fmaf(xv.w, w3.y, acc[ri].y))));
            acc[ri].z = fmaf(xv.x, w0.z, fmaf(xv.y, w1.z, fmaf(xv.z, w2v.z, fmaf(xv.w, w3.z, acc[ri].z))));
            acc[ri].w = fmaf(xv.x, w0.w, fmaf(xv.y, w1.w, fmaf(xv.z, w2v.w, fmaf(xv.w, w3.w, acc[ri].w))));
        }
    }

    float ps[4] = {0.f, 0.f, 0.f, 0.f}, pq[4] = {0.f, 0.f, 0.f, 0.f};
    float ca[4] = {cadd[4 * tx], cadd[4 * tx + 1], cadd[4 * tx + 2], cadd[4 * tx + 3]};
    float bb[4] = {b2l[4 * tx], b2l[4 * tx + 1], b2l[4 * tx + 2], b2l[4 * tx + 3]};
#pragma unroll
    for (int ri = 0; ri < 4; ++ri) {
        int r = r0 + 4 * ty + ri;
        if (r < n) {
            float sd = sdi[r];
            float4 v;
            v.x = acc[ri].x + sd * ca[0] + bb[0];
            v.y = acc[ri].y + sd * ca[1] + bb[1];
            v.z = acc[ri].z + sd * ca[2] + bb[2];
            v.w = acc[ri].w + sd * ca[3] + bb[3];
            *(float4*)&h2[(long long)r * 64 + 4 * tx] = v;
            ps[0] += v.x; ps[1] += v.y; ps[2] += v.z; ps[3] += v.w;
            pq[0] += v.x * v.x; pq[1] += v.y * v.y; pq[2] += v.z * v.z; pq[3] += v.w * v.w;
        }
    }
    __syncthreads();
    float* lsum = Xs;
    float* lsq  = Xs + 1024;
#pragma unroll
    for (int di = 0; di < 4; ++di) {
        lsum[ty * 64 + 4 * tx + di] = ps[di];
        lsq[ty * 64 + 4 * tx + di]  = pq[di];
    }
    __syncthreads();
    if (t < 64) {
        float s = 0.f, s2 = 0.f;
#pragma unroll
        for (int g = 0; g < 16; ++g) {
            s += lsum[g * 64 + t];
            s2 += lsq[g * 64 + t];
        }
        atomicAdd(&stats[t], s);
        atomicAdd(&stats[64 + t], s2);
    }
}

// ---- HGNN gather, depth-2 pipelined; BN applies bn+relu+bias to rows --------
template <bool BN>
__global__ __launch_bounds__(256) void hg_gather_kernel(const float* __restrict__ in,
                                                        const int* __restrict__ off,
                                                        const unsigned* __restrict__ ents,
                                                        const float* __restrict__ stats,
                                                        const float* __restrict__ gamma,
                                                        const float* __restrict__ beta,
                                                        const float* __restrict__ hbias,
                                                        float invN,
                                                        float* __restrict__ out, int n) {
    int node = blockIdx.x * 4 + (threadIdx.x >> 6);
    if (node >= n) return;
    int lane = threadIdx.x & 63;
    int sub = lane >> 4;
    int q = lane & 15;
    float sc[4], sh[4], hb[4];
    if (BN) {
#pragma unroll
        for (int c = 0; c < 4; ++c) {
            int col = q * 4 + c;
            float mu = stats[col] * invN;
            float var = stats[64 + col] * invN - mu * mu;
            float s = gamma[col] * rsqrtf(var + 1e-5f);
            sc[c] = s; sh[c] = beta[col] - mu * s; hb[c] = hbias[col];
        }
    }
    int e0 = off[node], e1 = off[node + 1];
    float4 acc = make_float4(0.f, 0.f, 0.f, 0.f);
    int e = e0 + sub;
    while (e + 4 < e1) {
        unsigned ta = ents[e], tb = ents[e + 4];
        float va_ = __half2float(__ushort_as_half((unsigned short)(ta & 0xffffu)));
        float vb_ = __half2float(__ushort_as_half((unsigned short)(tb & 0xffffu)));
        float4 a4 = *(const float4*)(in + (long long)(ta >> 16) * 64 + q * 4);
        float4 b4 = *(const float4*)(in + (long long)(tb >> 16) * 64 + q * 4);
        if (BN) {
            a4.x = fmaxf(fmaf(a4.x, sc[0], sh[0]), 0.f) + hb[0];
            a4.y = fmaxf(fmaf(a4.y, sc[1], sh[1]), 0.f) + hb[1];
            a4.z = fmaxf(fmaf(a4.z, sc[2], sh[2]), 0.f) + hb[2];
            a4.w = fmaxf(fmaf(a4.w, sc[3], sh[3]), 0.f) + hb[3];
            b4.x = fmaxf(fmaf(b4.x, sc[0], sh[0]), 0.f) + hb[0];
            b4.y = fmaxf(fmaf(b4.y, sc[1], sh[1]), 0.f) + hb[1];
            b4.z = fmaxf(fmaf(b4.z, sc[2], sh[2]), 0.f) + hb[2];
            b4.w = fmaxf(fmaf(b4.w, sc[3], sh[3]), 0.f) + hb[3];
        }
        acc.x = fmaf(va_, a4.x, fmaf(vb_, b4.x, acc.x));
        acc.y = fmaf(va_, a4.y, fmaf(vb_, b4.y, acc.y));
        acc.z = fmaf(va_, a4.z, fmaf(vb_, b4.z, acc.z));
        acc.w = fmaf(va_, a4.w, fmaf(vb_, b4.w, acc.w));
        e += 8;
    }
    if (e < e1) {
        unsigned ta = ents[e];
        float va_ = __half2float(__ushort_as_half((unsigned short)(ta & 0xffffu)));
        float4 a4 = *(const float4*)(in + (long long)(ta >> 16) * 64 + q * 4);
        if (BN) {
            a4.x = fmaxf(fmaf(a4.x, sc[0], sh[0]), 0.f) + hb[0];
            a4.y = fmaxf(fmaf(a4.y, sc[1], sh[1]), 0.f) + hb[1];
            a4.z = fmaxf(fmaf(a4.z, sc[2], sh[2]), 0.f) + hb[2];
            a4.w = fmaxf(fmaf(a4.w, sc[3], sh[3]), 0.f) + hb[3];
        }
        acc.x = fmaf(va_, a4.x, acc.x);
        acc.y = fmaf(va_, a4.y, acc.y);
        acc.z = fmaf(va_, a4.z, acc.z);
        acc.w = fmaf(va_, a4.w, acc.w);
    }
    acc.x += __shfl_xor(acc.x, 16, 64); acc.x += __shfl_xor(acc.x, 32, 64);
    acc.y += __shfl_xor(acc.y, 16, 64); acc.y += __shfl_xor(acc.y, 32, 64);
    acc.z += __shfl_xor(acc.z, 16, 64); acc.z += __shfl_xor(acc.z, 32, 64);
    acc.w += __shfl_xor(acc.w, 16, 64); acc.w += __shfl_xor(acc.w, 32, 64);
    if (sub == 0) *(float4*)(out + (long long)node * 64 + q * 4) = acc;
}

// ---- fused tail: softmax -> fc1 -> fusion gate; 32-row tile, WL in LDS ------
#define TPAD 68
#define TROWS 32
__device__ __forceinline__ float dot4(float4 a, float4 b) {
    return fmaf(a.x, b.x, fmaf(a.y, b.y, fmaf(a.z, b.z, a.w * b.w)));
}

__global__ __launch_bounds__(256) void tail_kernel(const float* __restrict__ x2,
                                                   const float* __restrict__ h2raw,
                                                   const float* __restrict__ fc1_W,
                                                   const float* __restrict__ fusW1,
                                                   const float* __restrict__ b1,
                                                   const float* __restrict__ w2,
                                                   const float* __restrict__ b2,
                                                   const float* __restrict__ stats,
                                                   const float* __restrict__ gamma,
                                                   const float* __restrict__ beta,
                                                   float invN,
                                                   float* __restrict__ out, int n) {
    __shared__ float A[TROWS * TPAD];   // P (softmax probs), later S (subn)
    __shared__ float Hs[TROWS * TPAD];  // hidden tile (bn applied)
    __shared__ float WL[64 * TPAD];     // fc1_W, later fus_l1_W
    __shared__ float bsc[64], bsh[64];
    int t = threadIdx.x;
    int tx = t & 15, ty = t >> 4;
    int r0 = blockIdx.x * TROWS;

    if (t < 64) {
        float mu = stats[t] * invN;
        float var = stats[64 + t] * invN - mu * mu;
        float s = gamma[t] * rsqrtf(var + 1e-5f);
        bsc[t] = s; bsh[t] = beta[t] - mu * s;
    }
    __syncthreads();

    float b1d[4], w2d[4];
#pragma unroll
    for (int di = 0; di < 4; ++di) {
        b1d[di] = b1[tx + 16 * di];
        w2d[di] = w2[tx + 16 * di];
    }
    float b20 = b2[0];

    // fc1 weights -> WL (64 rows); bn(hidden) tile -> Hs (32 rows)
    for (int f = t; f < 1024; f += 256) {
        int d = f >> 4, k4 = (f & 15) << 2;
        *(float4*)&WL[d * TPAD + k4] = *(const float4*)&fc1_W[d * 64 + k4];
    }
    for (int f = t; f < 512; f += 256) {
        int d = f >> 4, k4 = (f & 15) << 2;
        int gr = r0 + d;
        float4 hv = make_float4(0.f, 0.f, 0.f, 0.f);
        if (gr < n) {
            hv = *(const float4*)&h2raw[(long long)gr * 64 + k4];
            hv.x = fmaf(hv.x, bsc[k4],     bsh[k4]);
            hv.y = fmaf(hv.y, bsc[k4 + 1], bsh[k4 + 1]);
            hv.z = fmaf(hv.z, bsc[k4 + 2], bsh[k4 + 2]);
            hv.w = fmaf(hv.w, bsc[k4 + 3], bsh[k4 + 3]);
        }
        *(float4*)&Hs[d * TPAD + k4] = hv;
    }

    // x2 tile: load + row softmax -> A (2 rows per thread)
#pragma unroll
    for (int ri = 0; ri < 2; ++ri) {
        int rl = 2 * ty + ri;
        int r = r0 + rl;
        bool ok = r < n;
        float vv[4];
#pragma unroll
        for (int di = 0; di < 4; ++di)
            vv[di] = ok ? x2[(long long)r * 64 + tx + 16 * di] : 0.f;
        float m = fmaxf(fmaxf(vv[0], vv[1]), fmaxf(vv[2], vv[3]));
        for (int s = 1; s < 16; s <<= 1) m = fmaxf(m, __shfl_xor(m, s, 16));
        float e0 = __expf(vv[0] - m), e1 = __expf(vv[1] - m);
        float e2 = __expf(vv[2] - m), e3 = __expf(vv[3] - m);
        float sm = e0 + e1 + e2 + e3;
        for (int s = 1; s < 16; s <<= 1) sm += __shfl_xor(sm, s, 16);
        float inv = 1.0f / sm;
        A[rl * TPAD + tx]      = e0 * inv;
        A[rl * TPAD + tx + 16] = e1 * inv;
        A[rl * TPAD + tx + 32] = e2 * inv;
        A[rl * TPAD + tx + 48] = e3 * inv;
    }
    __syncthreads();

    // fc1: sn = P @ fc1_W^T
    float sn[2][4];
#pragma unroll
    for (int ri = 0; ri < 2; ++ri)
#pragma unroll
        for (int di = 0; di < 4; ++di) sn[ri][di] = 0.f;
    for (int k = 0; k < 64; k += 4) {
        float4 p4[2], w4[4];
#pragma unroll
        for (int ri = 0; ri < 2; ++ri) p4[ri] = *(float4*)&A[(2 * ty + ri) * TPAD + k];
#pragma unroll
        for (int di = 0; di < 4; ++di) w4[di] = *(float4*)&WL[(tx + 16 * di) * TPAD + k];
#pragma unroll
        for (int ri = 0; ri < 2; ++ri)
#pragma unroll
            for (int di = 0; di < 4; ++di)
                sn[ri][di] += dot4(p4[ri], w4[di]);
    }
    __syncthreads();

    // S (subn) -> A ; fus_l1_W -> WL
#pragma unroll
    for (int ri = 0; ri < 2; ++ri)
#pragma unroll
        for (int di = 0; di < 4; ++di)
            A[(2 * ty + ri) * TPAD + tx + 16 * di] = sn[ri][di];
    for (int f = t; f < 1024; f += 256) {
        int d = f >> 4, k4 = (f & 15) << 2;
        *(float4*)&WL[d * TPAD + k4] = *(const float4*)&fusW1[d * 64 + k4];
    }
    __syncthreads();

    // gates
    float aH[2][4], aS[2][4];
#pragma unroll
    for (int ri = 0; ri < 2; ++ri)
#pragma unroll
        for (int di = 0; di < 4; ++di) { aH[ri][di] = b1d[di]; aS[ri][di] = b1d[di]; }
    for (int k = 0; k < 64; k += 4) {
        float4 h4[2], s4[2], w4[4];
#pragma unroll
        for (int ri = 0; ri < 2; ++ri) {
            h4[ri] = *(float4*)&Hs[(2 * ty + ri) * TPAD + k];
            s4[ri] = *(float4*)&A[(2 * ty + ri) * TPAD + k];
        }
#pragma unroll
        for (int di = 0; di < 4; ++di) w4[di] = *(float4*)&WL[(tx + 16 * di) * TPAD + k];
#pragma unroll
        for (int ri = 0; ri < 2; ++ri)
#pragma unroll
            for (int di = 0; di < 4; ++di) {
                aH[ri][di] += dot4(h4[ri], w4[di]);
                aS[ri][di] += dot4(s4[ri], w4[di]);
            }
    }

#pragma unroll
    for (int ri = 0; ri < 2; ++ri) {
        int rl = 2 * ty + ri;
        int r = r0 + rl;
        float pH = 0.f, pS = 0.f;
#pragma unroll
        for (int di = 0; di < 4; ++di) {
            pH = fmaf(fast_tanh(aH[ri][di]), w2d[di], pH);
            pS = fmaf(fast_tanh(aS[ri][di]), w2d[di], pS);
        }
        for (int s = 1; s < 16; s <<= 1) {
            pH += __shfl_xor(pH, s, 16);
            pS += __shfl_xor(pS, s, 16);
        }
        pH += b20; pS += b20;
        float mx = fmaxf(pH, pS);
        float eH = __expf(pH - mx), eS = __expf(pS - mx);
        float inv = 1.0f / (eH + eS);
        if (r < n) {
#pragma unroll
            for (int di = 0; di < 4; ++di) {
                int d = tx + 16 * di;
                float hv = Hs[rl * TPAD + d];
                out[(long long)r * 64 + d] = (eH * hv + eS * sn[ri][di]) * inv;
            }
        }
    }
}

// ---------------------------------------------------------------------------
extern "C" void kernel_launch(void* const* d_in, const int* in_sizes, int n_in,
                              void* d_out, int out_size, void* d_ws, size_t ws_size,
                              hipStream_t stream) {
    const float* emb       = (const float*)d_in[0];
    const float* W1        = (const float*)d_in[1];
    const float* b1        = (const float*)d_in[2];
    const float* W2        = (const float*)d_in[3];
    const float* b2        = (const float*)d_in[4];
    const float* gamma     = (const float*)d_in[5];
    const float* beta      = (const float*)d_in[6];
    const float* hgc1_bias = (const float*)d_in[7];
    const float* fc1_W     = (const float*)d_in[8];
    const float* fus_l1_W  = (const float*)d_in[9];
    const float* fus_l1_b  = (const float*)d_in[10];
    const float* fus_l2_W  = (const float*)d_in[11];
    const float* fus_l2_b  = (const float*)d_in[12];
    const float* hg_val    = (const float*)d_in[13];
    const int*   edge_index= (const int*)d_in[14];
    const int*   hg_row    = (const int*)d_in[15];
    const int*   hg_col    = (const int*)d_in[16];

    const int N    = in_sizes[0] / 64;
    const int E    = in_sizes[14] / 2;
    const int NNZ  = in_sizes[13];
    const int Np   = (N + 3) & ~3;
    const int NSEG = (N + 255) >> 8;
    const int* src = edge_index;
    const int* dst = edge_index + E;

    float* ws      = (float*)d_ws;
    float* dinv    = ws;
    float* sdi     = dinv + Np;
    float* w12     = sdi + Np;
    float* bw      = w12 + 4096;
    float* stats   = bw + 64;
    int*   gcn_off = (int*)(stats + 128);
    int*   hgc_off = gcn_off + (Np + 4);
    int*   hgr_off = hgc_off + (Np + 4);
    int*   segtot  = hgr_off + (Np + 4);
    int*   segoff  = segtot + 3 * NSEG;
    int*   blockcnt= segoff + 3 * NSEG;
    unsigned short* gcn_srcs = (unsigned short*)(blockcnt + 3 * NSEG * PBLK);
    unsigned* hgc_ent = (unsigned*)(gcn_srcs + ((E + 1) & ~1));
    unsigned* hgr_ent = hgc_ent + NNZ;
    float* buf1    = (float*)(hgr_ent + NNZ);
    float* buf2    = buf1 + (size_t)128 * Np;

    const int Ep = (E + 1) & ~1;
    unsigned* runG = (unsigned*)buf1;
    uint2*    runC = (uint2*)(runG + Ep);
    uint2*    runR = runC + NNZ;

    float* tbuf = buf2;                      // A-hat emb        N x 64
    float* ubuf = buf1;                      // A-hat^2 emb      N x 64
    float* h2   = buf1 + (size_t)64 * Np;    // raw h2 (pre-bn)  N x 64
    float* eemb = buf2;                      // edge emb         N x 64 (tbuf dead)
    float* x2   = buf1;                      // HGNN out         N x 64 (ubuf dead)
    float* out  = (float*)d_out;

    const float invN = 1.0f / (float)N;

    // --- CSR build: count -> scans -> scatter runs -> per-seg csr_build ---
    hipMemsetAsync(stats, 0, 128 * sizeof(float), stream);
    p1_count_kernel<<<PBLK, 256, 0, stream>>>(dst, E, hg_row, hg_col, NNZ, blockcnt, NSEG);
    p2a_kernel<<<(3 * NSEG + 3) / 4, 256, 0, stream>>>(blockcnt, segtot, 3 * NSEG);
    p2b_kernel<<<1, 192, 0, stream>>>(segtot, segoff, NSEG);
    p3_scatter_kernel<<<PBLK, 256, 0, stream>>>(src, dst, E, hg_row, hg_col, hg_val, NNZ,
                                                blockcnt, segoff, runG, runC, runR, NSEG);
    csr_build_kernel<<<NSEG, 256, 0, stream>>>(runG, runC, runR, segoff, segtot, NSEG, N,
                                               gcn_off, hgc_off, hgr_off, dinv,
                                               gcn_srcs, hgc_ent, hgr_ent);

    // --- weight precompute + reassociated GCN ---
    wprep_kernel<<<65, 64, 0, stream>>>(W1, W2, b1, w12, bw);
    gcn_gather_kernel<true><<<(N + 3) / 4, 256, 0, stream>>>(emb, dinv, gcn_off, gcn_srcs,
                                                             tbuf, sdi, N);
    gcn_gather_kernel<false><<<(N + 3) / 4, 256, 0, stream>>>(tbuf, dinv, gcn_off, gcn_srcs,
                                                              ubuf, nullptr, N);
    gemm_h2_kernel<<<(N + 63) / 64, 256, 0, stream>>>(ubuf, w12, bw, b2, sdi, h2, stats, N);

    // --- HGNN: edge_emb = G^T relu(bn(h2))+bias ; x2 = G edge_emb ---
    hg_gather_kernel<true><<<(N + 3) / 4, 256, 0, stream>>>(h2, hgc_off, hgc_ent,
                                                            stats, gamma, beta, hgc1_bias,
                                                            invN, eemb, N);
    hg_gather_kernel<false><<<(N + 3) / 4, 256, 0, stream>>>(eemb, hgr_off, hgr_ent,
                                                             nullptr, nullptr, nullptr, nullptr,
                                                             0.f, x2, N);

    // --- fused softmax + fc1 + fusion gate (bn on hidden inline) ---
    tail_kernel<<<(N + TROWS - 1) / TROWS, 256, 0, stream>>>(x2, h2, fc1_W, fus_l1_W, fus_l1_b,
                                                             fus_l2_W, fus_l2_b, stats, gamma, beta,
                                                             invN, out, N);
}

// Round 17
// 274.508 us; speedup vs baseline: 1.1502x; 1.0165x over previous
//
#include <hip/hip_runtime.h>
#include <hip/hip_fp16.h>

// ---------------------------------------------------------------------------
// MSHGAT forward, round 17:
//  - hipMemsetAsync(stats, 512B) removed: the runtime fill-blit cost ~42us
//    per graph replay (top-1 dispatch in R16!). stats zeroing folded into
//    wprep_kernel block 64 (stream-ordered before gemm_h2's accumulation).
//  - everything else unchanged from R16 (32-row tail tile, depth-2 gathers,
//    fine-seg radix CSR build, reassociated GCN, fused BN).
// N=50000, D=64, E=600000, NNZ=800000.
// ---------------------------------------------------------------------------

#define SEGSH 8      // seg = key >> 8 (256 keys per seg)
#define MAXSEG 256   // supports N <= 65536
#define PBLK 256     // partition blocks (p1/p3)

__device__ __forceinline__ float fast_tanh(float x) {
    float xc = fminf(fmaxf(x, -15.f), 15.f);
    float e = __expf(2.f * xc);
    return (e - 1.f) / (e + 1.f);
}

// ---- P1: per-block per-(stream,seg) counts ----------------------------------
__global__ __launch_bounds__(256) void p1_count_kernel(const int* __restrict__ dst, int e,
                                                       const int* __restrict__ row,
                                                       const int* __restrict__ col, int nnz,
                                                       int* __restrict__ blockcnt, int nseg) {
    __shared__ int lc[3 * MAXSEG];
    for (int i = threadIdx.x; i < 3 * nseg; i += 256) lc[i] = 0;
    __syncthreads();
    int ce = (e + PBLK - 1) / PBLK;
    int cz = (nnz + PBLK - 1) / PBLK;
    int e0 = blockIdx.x * ce, e1 = min(e0 + ce, e);
    for (int i = e0 + threadIdx.x; i < e1; i += 256)
        atomicAdd(&lc[dst[i] >> SEGSH], 1);
    int z0 = blockIdx.x * cz, z1 = min(z0 + cz, nnz);
    for (int i = z0 + threadIdx.x; i < z1; i += 256) {
        atomicAdd(&lc[nseg + (col[i] >> SEGSH)], 1);
        atomicAdd(&lc[2 * nseg + (row[i] >> SEGSH)], 1);
    }
    __syncthreads();
    for (int r = threadIdx.x; r < 3 * nseg; r += 256)
        blockcnt[r * PBLK + blockIdx.x] = lc[r];
}

// ---- P2a: per-row (stream,seg) exclusive scan over the PBLK block counts ----
__global__ __launch_bounds__(256) void p2a_kernel(int* __restrict__ blockcnt,
                                                  int* __restrict__ segtot, int rows) {
    int rw = blockIdx.x * 4 + (threadIdx.x >> 6);
    if (rw >= rows) return;
    int ln = threadIdx.x & 63;
    int b = rw * PBLK + ln * 4;
    int v0 = blockcnt[b], v1 = blockcnt[b + 1], v2 = blockcnt[b + 2], v3 = blockcnt[b + 3];
    int s = v0 + v1 + v2 + v3;
    int incl = s;
    for (int d = 1; d < 64; d <<= 1) {
        int t = __shfl_up(incl, d, 64);
        if (ln >= d) incl += t;
    }
    int excl = incl - s;
    blockcnt[b]     = excl;
    blockcnt[b + 1] = excl + v0;
    blockcnt[b + 2] = excl + v0 + v1;
    blockcnt[b + 3] = excl + v0 + v1 + v2;
    if (ln == 63) segtot[rw] = incl;
}

// ---- P2b: per-stream exclusive scan over seg totals -> segoff ---------------
__global__ __launch_bounds__(192) void p2b_kernel(const int* __restrict__ segtot,
                                                  int* __restrict__ segoff, int nseg) {
    int st = threadIdx.x >> 6, ln = threadIdx.x & 63;
    int chunk = (nseg + 63) / 64;
    int s0 = ln * chunk, s1 = min(s0 + chunk, nseg);
    int sum = 0;
    for (int i = s0; i < s1; ++i) sum += segtot[st * nseg + i];
    int incl = sum;
    for (int d = 1; d < 64; d <<= 1) {
        int v = __shfl_up(incl, d, 64);
        if (ln >= d) incl += v;
    }
    int run = incl - sum;
    for (int i = s0; i < s1; ++i) {
        segoff[st * nseg + i] = run;
        run += segtot[st * nseg + i];
    }
}

// ---- P3: scatter entries into per-seg runs (pre-scanned bases) --------------
__global__ __launch_bounds__(256) void p3_scatter_kernel(const int* __restrict__ src,
                                                         const int* __restrict__ dst, int e,
                                                         const int* __restrict__ row,
                                                         const int* __restrict__ col,
                                                         const float* __restrict__ val, int nnz,
                                                         const int* __restrict__ blockcnt,
                                                         const int* __restrict__ segoff,
                                                         unsigned* __restrict__ runG,
                                                         uint2* __restrict__ runC,
                                                         uint2* __restrict__ runR, int nseg) {
    __shared__ int base[3 * MAXSEG];
    __shared__ int cnt[3 * MAXSEG];
    for (int i = threadIdx.x; i < 3 * nseg; i += 256) {
        base[i] = segoff[i] + blockcnt[i * PBLK + blockIdx.x];
        cnt[i] = 0;
    }
    __syncthreads();
    int ce = (e + PBLK - 1) / PBLK;
    int cz = (nnz + PBLK - 1) / PBLK;
    int e0 = blockIdx.x * ce, e1 = min(e0 + ce, e);
    for (int i = e0 + threadIdx.x; i < e1; i += 256) {
        int d = dst[i];
        int sg = d >> SEGSH;
        int p = atomicAdd(&cnt[sg], 1);
        runG[base[sg] + p] = ((unsigned)d << 16) | (unsigned)src[i];
    }
    int z0 = blockIdx.x * cz, z1 = min(z0 + cz, nnz);
    for (int i = z0 + threadIdx.x; i < z1; i += 256) {
        int r = row[i], c = col[i];
        unsigned hv = (unsigned)__half_as_ushort(__float2half(val[i]));
        int sgc = nseg + (c >> SEGSH);
        int p = atomicAdd(&cnt[sgc], 1);
        runC[base[sgc] + p] = make_uint2((unsigned)c, ((unsigned)r << 16) | hv);
        int sgr = 2 * nseg + (r >> SEGSH);
        p = atomicAdd(&cnt[sgr], 1);
        runR[base[sgr] + p] = make_uint2((unsigned)r, ((unsigned)c << 16) | hv);
    }
}

// ---- CSR build: one block per seg. count -> scan (off, dinv) -> scatter -----
__global__ __launch_bounds__(256) void csr_build_kernel(const unsigned* __restrict__ runG,
                                                        const uint2* __restrict__ runC,
                                                        const uint2* __restrict__ runR,
                                                        const int* __restrict__ segoff,
                                                        const int* __restrict__ segtot,
                                                        int nseg, int n,
                                                        int* __restrict__ gcn_off,
                                                        int* __restrict__ hgc_off,
                                                        int* __restrict__ hgr_off,
                                                        float* __restrict__ dinv,
                                                        unsigned short* __restrict__ gsrcs,
                                                        unsigned* __restrict__ entc,
                                                        unsigned* __restrict__ entr) {
    __shared__ int cG[256], cC[256], cR[256];
    int s = blockIdx.x;
    int t = threadIdx.x;
    cG[t] = 0; cC[t] = 0; cR[t] = 0;
    __syncthreads();
    int oG = segoff[s],            nG = segtot[s];
    int oC = segoff[nseg + s],     nC = segtot[nseg + s];
    int oR = segoff[2 * nseg + s], nR = segtot[2 * nseg + s];
    for (int i = t; i < nG; i += 256) atomicAdd(&cG[(runG[oG + i] >> 16) & 255], 1);
    for (int i = t; i < nC; i += 256) atomicAdd(&cC[runC[oC + i].x & 255], 1);
    for (int i = t; i < nR; i += 256) atomicAdd(&cR[runR[oR + i].x & 255], 1);
    __syncthreads();
    int vG = cG[t], vC = cC[t], vR = cR[t];
    for (int d = 1; d < 256; d <<= 1) {
        int tG = (t >= d) ? cG[t - d] : 0;
        int tC = (t >= d) ? cC[t - d] : 0;
        int tR = (t >= d) ? cR[t - d] : 0;
        __syncthreads();
        cG[t] += tG; cC[t] += tC; cR[t] += tR;
        __syncthreads();
    }
    int eG = cG[t] - vG, eC = cC[t] - vC, eR = cR[t] - vR;
    int key = (s << SEGSH) + t;
    if (key < n) {
        gcn_off[key] = oG + eG;
        hgc_off[key] = oC + eC;
        hgr_off[key] = oR + eR;
        dinv[key] = rsqrtf((float)(vG + 1));
    }
    if (key == n) {
        gcn_off[n] = oG + eG;
        hgc_off[n] = oC + eC;
        hgr_off[n] = oR + eR;
    }
    if (s == nseg - 1 && t == 255 && ((n & 255) == 0)) {
        gcn_off[n] = oG + cG[255];
        hgc_off[n] = oC + cC[255];
        hgr_off[n] = oR + cR[255];
    }
    __syncthreads();
    cG[t] = oG + eG; cC[t] = oC + eC; cR[t] = oR + eR;
    __syncthreads();
    for (int i = t; i < nG; i += 256) {
        unsigned u = runG[oG + i];
        int p = atomicAdd(&cG[(u >> 16) & 255], 1);
        gsrcs[p] = (unsigned short)(u & 0xffffu);
    }
    for (int i = t; i < nC; i += 256) {
        uint2 u = runC[oC + i];
        int p = atomicAdd(&cC[u.x & 255], 1);
        entc[p] = u.y;
    }
    for (int i = t; i < nR; i += 256) {
        uint2 u = runR[oR + i];
        int p = atomicAdd(&cR[u.x & 255], 1);
        entr[p] = u.y;
    }
}

// ---- weight precompute: W12 = W1@W2, bw = b1@W2; block 64 zeroes stats ------
__global__ __launch_bounds__(64) void wprep_kernel(const float* __restrict__ W1,  // 64x128
                                                   const float* __restrict__ W2,  // 128x64
                                                   const float* __restrict__ b1,  // 128
                                                   float* __restrict__ W12,
                                                   float* __restrict__ bw,
                                                   float* __restrict__ stats) {
    int r = blockIdx.x;
    int c = threadIdx.x;
    if (r == 64) {                       // zero stats alongside bw (replaces memset)
        stats[c] = 0.f;
        stats[64 + c] = 0.f;
    }
    const float* a = (r < 64) ? (W1 + r * 128) : b1;
    float acc = 0.f;
#pragma unroll 8
    for (int k = 0; k < 128; ++k) acc = fmaf(a[k], W2[k * 64 + c], acc);
    if (r < 64) W12[r * 64 + c] = acc;
    else bw[c] = acc;
}

// ---- GCN gather (normalized), depth-2 pipelined ------------------------------
template <bool SDI>
__global__ __launch_bounds__(256) void gcn_gather_kernel(const float* __restrict__ x,
                                                         const float* __restrict__ dinv,
                                                         const int* __restrict__ off,
                                                         const unsigned short* __restrict__ srcs,
                                                         float* __restrict__ out,
                                                         float* __restrict__ sdi, int n) {
    int node = blockIdx.x * 4 + (threadIdx.x >> 6);
    if (node >= n) return;
    int lane = threadIdx.x & 63;
    int sub = lane >> 4;
    int q = lane & 15;
    int e0 = off[node], e1 = off[node + 1];
    float4 acc = make_float4(0.f, 0.f, 0.f, 0.f);
    float dsum = 0.f;
    int e = e0 + sub;
    while (e + 4 < e1) {
        int sa = srcs[e], sb = srcs[e + 4];
        float da = dinv[sa], db = dinv[sb];
        const float4 va = *(const float4*)(x + (long long)sa * 64 + q * 4);
        const float4 vb = *(const float4*)(x + (long long)sb * 64 + q * 4);
        acc.x = fmaf(da, va.x, fmaf(db, vb.x, acc.x));
        acc.y = fmaf(da, va.y, fmaf(db, vb.y, acc.y));
        acc.z = fmaf(da, va.z, fmaf(db, vb.z, acc.z));
        acc.w = fmaf(da, va.w, fmaf(db, vb.w, acc.w));
        dsum += da + db;
        e += 8;
    }
    if (e < e1) {
        int sa = srcs[e];
        float da = dinv[sa];
        const float4 va = *(const float4*)(x + (long long)sa * 64 + q * 4);
        acc.x = fmaf(da, va.x, acc.x);
        acc.y = fmaf(da, va.y, acc.y);
        acc.z = fmaf(da, va.z, acc.z);
        acc.w = fmaf(da, va.w, acc.w);
        dsum += da;
    }
    acc.x += __shfl_xor(acc.x, 16, 64); acc.x += __shfl_xor(acc.x, 32, 64);
    acc.y += __shfl_xor(acc.y, 16, 64); acc.y += __shfl_xor(acc.y, 32, 64);
    acc.z += __shfl_xor(acc.z, 16, 64); acc.z += __shfl_xor(acc.z, 32, 64);
    acc.w += __shfl_xor(acc.w, 16, 64); acc.w += __shfl_xor(acc.w, 32, 64);
    if (SDI) { dsum += __shfl_xor(dsum, 16, 64); dsum += __shfl_xor(dsum, 32, 64); }
    if (sub == 0) {
        float dt = dinv[node];
        const float4 xs = *(const float4*)(x + (long long)node * 64 + q * 4);
        float4 o;
        o.x = dt * fmaf(dt, xs.x, acc.x);
        o.y = dt * fmaf(dt, xs.y, acc.y);
        o.z = dt * fmaf(dt, xs.z, acc.z);
        o.w = dt * fmaf(dt, xs.w, acc.w);
        *(float4*)(out + (long long)node * 64 + q * 4) = o;
        if (SDI && q == 0) sdi[node] = dt * (dt + dsum);
    }
}

// ---- GEMM h2 = u @ W12 + sdi[r]*bw + b2 : register-tiled, fused BN stats ----
#define GP 68
__global__ __launch_bounds__(256) void gemm_h2_kernel(const float* __restrict__ X,
                                                      const float* __restrict__ W12,
                                                      const float* __restrict__ bw,
                                                      const float* __restrict__ b2,
                                                      const float* __restrict__ sdi,
                                                      float* __restrict__ h2,
                                                      float* __restrict__ stats, int n) {
    __shared__ float Xs[64 * GP];
    __shared__ float WL[64 * GP];
    __shared__ float cadd[64], b2l[64];
    int t = threadIdx.x;
    int tx = t & 15, ty = t >> 4;
    int r0 = blockIdx.x * 64;
    if (t < 64) cadd[t] = bw[t];
    else if (t < 128) b2l[t - 64] = b2[t - 64];
    for (int f = t; f < 1024; f += 256) {
        int d = f >> 4, k4 = (f & 15) << 2;
        *(float4*)&WL[d * GP + k4] = *(const float4*)&W12[d * 64 + k4];
        int gr = r0 + d;
        float4 xv = make_float4(0.f, 0.f, 0.f, 0.f);
        if (gr < n) xv = *(const float4*)&X[(long long)gr * 64 + k4];
        *(float4*)&Xs[d * GP + k4] = xv;
    }
    __syncthreads();

    float4 acc[4];
#pragma unroll
    for (int ri = 0; ri < 4; ++ri) acc[ri] = make_float4(0.f, 0.f, 0.f, 0.f);
    for (int k = 0; k < 64; k += 4) {
        float4 w0 = *(float4*)&WL[(k + 0) * GP + 4 * tx];
        float4 w1 = *(float4*)&WL[(k + 1) * GP + 4 * tx];
        float4 w2v = *(float4*)&WL[(k + 2) * GP + 4 * tx];
        float4 w3 = *(float4*)&WL[(k + 3) * GP + 4 * tx];
#pragma unroll
        for (int ri = 0; ri < 4; ++ri) {
            float4 xv = *(float4*)&Xs[(4 * ty + ri) * GP + k];
            acc[ri].x = fmaf(xv.x, w0.x, fmaf(xv.y, w1.x, fmaf(xv.z, w2v.x, fmaf(xv.w, w3.x, acc[ri].x))));
            acc[ri].y = fmaf(xv.x, w0.y, fmaf(xv.y, w1.y, fmaf(xv.z, w2v.y, fmaf(xv.w, w3.y, acc[ri].y))));
            acc[ri].z = fmaf(xv.x, w0.z, fmaf(xv.y, w1.z, fmaf(xv.z, w2v.z, fmaf(xv.w, w3.z, acc[ri].z))));
            acc[ri].w = fmaf(xv.x, w0.w, fmaf(xv.y, w1.w, fmaf(xv.z, w2v.w, fmaf(xv.w, w3.w, acc[ri].w))));
        }
    }

    float ps[4] = {0.f, 0.f, 0.f, 0.f}, pq[4] = {0.f, 0.f, 0.f, 0.f};
    float ca[4] = {cadd[4 * tx], cadd[4 * tx + 1], cadd[4 * tx + 2], cadd[4 * tx + 3]};
    float bb[4] = {b2l[4 * tx], b2l[4 * tx + 1], b2l[4 * tx + 2], b2l[4 * tx + 3]};
#pragma unroll
    for (int ri = 0; ri < 4; ++ri) {
        int r = r0 + 4 * ty + ri;
        if (r < n) {
            float sd = sdi[r];
            float4 v;
            v.x = acc[ri].x + sd * ca[0] + bb[0];
            v.y = acc[ri].y + sd * ca[1] + bb[1];
            v.z = acc[ri].z + sd * ca[2] + bb[2];
            v.w = acc[ri].w + sd * ca[3] + bb[3];
            *(float4*)&h2[(long long)r * 64 + 4 * tx] = v;
            ps[0] += v.x; ps[1] += v.y; ps[2] += v.z; ps[3] += v.w;
            pq[0] += v.x * v.x; pq[1] += v.y * v.y; pq[2] += v.z * v.z; pq[3] += v.w * v.w;
        }
    }
    __syncthreads();
    float* lsum = Xs;
    float* lsq  = Xs + 1024;
#pragma unroll
    for (int di = 0; di < 4; ++di) {
        lsum[ty * 64 + 4 * tx + di] = ps[di];
        lsq[ty * 64 + 4 * tx + di]  = pq[di];
    }
    __syncthreads();
    if (t < 64) {
        float s = 0.f, s2 = 0.f;
#pragma unroll
        for (int g = 0; g < 16; ++g) {
            s += lsum[g * 64 + t];
            s2 += lsq[g * 64 + t];
        }
        atomicAdd(&stats[t], s);
        atomicAdd(&stats[64 + t], s2);
    }
}

// ---- HGNN gather, depth-2 pipelined; BN applies bn+relu+bias to rows --------
template <bool BN>
__global__ __launch_bounds__(256) void hg_gather_kernel(const float* __restrict__ in,
                                                        const int* __restrict__ off,
                                                        const unsigned* __restrict__ ents,
                                                        const float* __restrict__ stats,
                                                        const float* __restrict__ gamma,
                                                        const float* __restrict__ beta,
                                                        const float* __restrict__ hbias,
                                                        float invN,
                                                        float* __restrict__ out, int n) {
    int node = blockIdx.x * 4 + (threadIdx.x >> 6);
    if (node >= n) return;
    int lane = threadIdx.x & 63;
    int sub = lane >> 4;
    int q = lane & 15;
    float sc[4], sh[4], hb[4];
    if (BN) {
#pragma unroll
        for (int c = 0; c < 4; ++c) {
            int col = q * 4 + c;
            float mu = stats[col] * invN;
            float var = stats[64 + col] * invN - mu * mu;
            float s = gamma[col] * rsqrtf(var + 1e-5f);
            sc[c] = s; sh[c] = beta[col] - mu * s; hb[c] = hbias[col];
        }
    }
    int e0 = off[node], e1 = off[node + 1];
    float4 acc = make_float4(0.f, 0.f, 0.f, 0.f);
    int e = e0 + sub;
    while (e + 4 < e1) {
        unsigned ta = ents[e], tb = ents[e + 4];
        float va_ = __half2float(__ushort_as_half((unsigned short)(ta & 0xffffu)));
        float vb_ = __half2float(__ushort_as_half((unsigned short)(tb & 0xffffu)));
        float4 a4 = *(const float4*)(in + (long long)(ta >> 16) * 64 + q * 4);
        float4 b4 = *(const float4*)(in + (long long)(tb >> 16) * 64 + q * 4);
        if (BN) {
            a4.x = fmaxf(fmaf(a4.x, sc[0], sh[0]), 0.f) + hb[0];
            a4.y = fmaxf(fmaf(a4.y, sc[1], sh[1]), 0.f) + hb[1];
            a4.z = fmaxf(fmaf(a4.z, sc[2], sh[2]), 0.f) + hb[2];
            a4.w = fmaxf(fmaf(a4.w, sc[3], sh[3]), 0.f) + hb[3];
            b4.x = fmaxf(fmaf(b4.x, sc[0], sh[0]), 0.f) + hb[0];
            b4.y = fmaxf(fmaf(b4.y, sc[1], sh[1]), 0.f) + hb[1];
            b4.z = fmaxf(fmaf(b4.z, sc[2], sh[2]), 0.f) + hb[2];
            b4.w = fmaxf(fmaf(b4.w, sc[3], sh[3]), 0.f) + hb[3];
        }
        acc.x = fmaf(va_, a4.x, fmaf(vb_, b4.x, acc.x));
        acc.y = fmaf(va_, a4.y, fmaf(vb_, b4.y, acc.y));
        acc.z = fmaf(va_, a4.z, fmaf(vb_, b4.z, acc.z));
        acc.w = fmaf(va_, a4.w, fmaf(vb_, b4.w, acc.w));
        e += 8;
    }
    if (e < e1) {
        unsigned ta = ents[e];
        float va_ = __half2float(__ushort_as_half((unsigned short)(ta & 0xffffu)));
        float4 a4 = *(const float4*)(in + (long long)(ta >> 16) * 64 + q * 4);
        if (BN) {
            a4.x = fmaxf(fmaf(a4.x, sc[0], sh[0]), 0.f) + hb[0];
            a4.y = fmaxf(fmaf(a4.y, sc[1], sh[1]), 0.f) + hb[1];
            a4.z = fmaxf(fmaf(a4.z, sc[2], sh[2]), 0.f) + hb[2];
            a4.w = fmaxf(fmaf(a4.w, sc[3], sh[3]), 0.f) + hb[3];
        }
        acc.x = fmaf(va_, a4.x, acc.x);
        acc.y = fmaf(va_, a4.y, acc.y);
        acc.z = fmaf(va_, a4.z, acc.z);
        acc.w = fmaf(va_, a4.w, acc.w);
    }
    acc.x += __shfl_xor(acc.x, 16, 64); acc.x += __shfl_xor(acc.x, 32, 64);
    acc.y += __shfl_xor(acc.y, 16, 64); acc.y += __shfl_xor(acc.y, 32, 64);
    acc.z += __shfl_xor(acc.z, 16, 64); acc.z += __shfl_xor(acc.z, 32, 64);
    acc.w += __shfl_xor(acc.w, 16, 64); acc.w += __shfl_xor(acc.w, 32, 64);
    if (sub == 0) *(float4*)(out + (long long)node * 64 + q * 4) = acc;
}

// ---- fused tail: softmax -> fc1 -> fusion gate; 32-row tile, WL in LDS ------
#define TPAD 68
#define TROWS 32
__device__ __forceinline__ float dot4(float4 a, float4 b) {
    return fmaf(a.x, b.x, fmaf(a.y, b.y, fmaf(a.z, b.z, a.w * b.w)));
}

__global__ __launch_bounds__(256) void tail_kernel(const float* __restrict__ x2,
                                                   const float* __restrict__ h2raw,
                                                   const float* __restrict__ fc1_W,
                                                   const float* __restrict__ fusW1,
                                                   const float* __restrict__ b1,
                                                   const float* __restrict__ w2,
                                                   const float* __restrict__ b2,
                                                   const float* __restrict__ stats,
                                                   const float* __restrict__ gamma,
                                                   const float* __restrict__ beta,
                                                   float invN,
                                                   float* __restrict__ out, int n) {
    __shared__ float A[TROWS * TPAD];   // P (softmax probs), later S (subn)
    __shared__ float Hs[TROWS * TPAD];  // hidden tile (bn applied)
    __shared__ float WL[64 * TPAD];     // fc1_W, later fus_l1_W
    __shared__ float bsc[64], bsh[64];
    int t = threadIdx.x;
    int tx = t & 15, ty = t >> 4;
    int r0 = blockIdx.x * TROWS;

    if (t < 64) {
        float mu = stats[t] * invN;
        float var = stats[64 + t] * invN - mu * mu;
        float s = gamma[t] * rsqrtf(var + 1e-5f);
        bsc[t] = s; bsh[t] = beta[t] - mu * s;
    }
    __syncthreads();

    float b1d[4], w2d[4];
#pragma unroll
    for (int di = 0; di < 4; ++di) {
        b1d[di] = b1[tx + 16 * di];
        w2d[di] = w2[tx + 16 * di];
    }
    float b20 = b2[0];

    for (int f = t; f < 1024; f += 256) {
        int d = f >> 4, k4 = (f & 15) << 2;
        *(float4*)&WL[d * TPAD + k4] = *(const float4*)&fc1_W[d * 64 + k4];
    }
    for (int f = t; f < 512; f += 256) {
        int d = f >> 4, k4 = (f & 15) << 2;
        int gr = r0 + d;
        float4 hv = make_float4(0.f, 0.f, 0.f, 0.f);
        if (gr < n) {
            hv = *(const float4*)&h2raw[(long long)gr * 64 + k4];
            hv.x = fmaf(hv.x, bsc[k4],     bsh[k4]);
            hv.y = fmaf(hv.y, bsc[k4 + 1], bsh[k4 + 1]);
            hv.z = fmaf(hv.z, bsc[k4 + 2], bsh[k4 + 2]);
            hv.w = fmaf(hv.w, bsc[k4 + 3], bsh[k4 + 3]);
        }
        *(float4*)&Hs[d * TPAD + k4] = hv;
    }

#pragma unroll
    for (int ri = 0; ri < 2; ++ri) {
        int rl = 2 * ty + ri;
        int r = r0 + rl;
        bool ok = r < n;
        float vv[4];
#pragma unroll
        for (int di = 0; di < 4; ++di)
            vv[di] = ok ? x2[(long long)r * 64 + tx + 16 * di] : 0.f;
        float m = fmaxf(fmaxf(vv[0], vv[1]), fmaxf(vv[2], vv[3]));
        for (int s = 1; s < 16; s <<= 1) m = fmaxf(m, __shfl_xor(m, s, 16));
        float e0 = __expf(vv[0] - m), e1 = __expf(vv[1] - m);
        float e2 = __expf(vv[2] - m), e3 = __expf(vv[3] - m);
        float sm = e0 + e1 + e2 + e3;
        for (int s = 1; s < 16; s <<= 1) sm += __shfl_xor(sm, s, 16);
        float inv = 1.0f / sm;
        A[rl * TPAD + tx]      = e0 * inv;
        A[rl * TPAD + tx + 16] = e1 * inv;
        A[rl * TPAD + tx + 32] = e2 * inv;
        A[rl * TPAD + tx + 48] = e3 * inv;
    }
    __syncthreads();

    float sn[2][4];
#pragma unroll
    for (int ri = 0; ri < 2; ++ri)
#pragma unroll
        for (int di = 0; di < 4; ++di) sn[ri][di] = 0.f;
    for (int k = 0; k < 64; k += 4) {
        float4 p4[2], w4[4];
#pragma unroll
        for (int ri = 0; ri < 2; ++ri) p4[ri] = *(float4*)&A[(2 * ty + ri) * TPAD + k];
#pragma unroll
        for (int di = 0; di < 4; ++di) w4[di] = *(float4*)&WL[(tx + 16 * di) * TPAD + k];
#pragma unroll
        for (int ri = 0; ri < 2; ++ri)
#pragma unroll
            for (int di = 0; di < 4; ++di)
                sn[ri][di] += dot4(p4[ri], w4[di]);
    }
    __syncthreads();

#pragma unroll
    for (int ri = 0; ri < 2; ++ri)
#pragma unroll
        for (int di = 0; di < 4; ++di)
            A[(2 * ty + ri) * TPAD + tx + 16 * di] = sn[ri][di];
    for (int f = t; f < 1024; f += 256) {
        int d = f >> 4, k4 = (f & 15) << 2;
        *(float4*)&WL[d * TPAD + k4] = *(const float4*)&fusW1[d * 64 + k4];
    }
    __syncthreads();

    float aH[2][4], aS[2][4];
#pragma unroll
    for (int ri = 0; ri < 2; ++ri)
#pragma unroll
        for (int di = 0; di < 4; ++di) { aH[ri][di] = b1d[di]; aS[ri][di] = b1d[di]; }
    for (int k = 0; k < 64; k += 4) {
        float4 h4[2], s4[2], w4[4];
#pragma unroll
        for (int ri = 0; ri < 2; ++ri) {
            h4[ri] = *(float4*)&Hs[(2 * ty + ri) * TPAD + k];
            s4[ri] = *(float4*)&A[(2 * ty + ri) * TPAD + k];
        }
#pragma unroll
        for (int di = 0; di < 4; ++di) w4[di] = *(float4*)&WL[(tx + 16 * di) * TPAD + k];
#pragma unroll
        for (int ri = 0; ri < 2; ++ri)
#pragma unroll
            for (int di = 0; di < 4; ++di) {
                aH[ri][di] += dot4(h4[ri], w4[di]);
                aS[ri][di] += dot4(s4[ri], w4[di]);
            }
    }

#pragma unroll
    for (int ri = 0; ri < 2; ++ri) {
        int rl = 2 * ty + ri;
        int r = r0 + rl;
        float pH = 0.f, pS = 0.f;
#pragma unroll
        for (int di = 0; di < 4; ++di) {
            pH = fmaf(fast_tanh(aH[ri][di]), w2d[di], pH);
            pS = fmaf(fast_tanh(aS[ri][di]), w2d[di], pS);
        }
        for (int s = 1; s < 16; s <<= 1) {
            pH += __shfl_xor(pH, s, 16);
            pS += __shfl_xor(pS, s, 16);
        }
        pH += b20; pS += b20;
        float mx = fmaxf(pH, pS);
        float eH = __expf(pH - mx), eS = __expf(pS - mx);
        float inv = 1.0f / (eH + eS);
        if (r < n) {
#pragma unroll
            for (int di = 0; di < 4; ++di) {
                int d = tx + 16 * di;
                float hv = Hs[rl * TPAD + d];
                out[(long long)r * 64 + d] = (eH * hv + eS * sn[ri][di]) * inv;
            }
        }
    }
}

// ---------------------------------------------------------------------------
extern "C" void kernel_launch(void* const* d_in, const int* in_sizes, int n_in,
                              void* d_out, int out_size, void* d_ws, size_t ws_size,
                              hipStream_t stream) {
    const float* emb       = (const float*)d_in[0];
    const float* W1        = (const float*)d_in[1];
    const float* b1        = (const float*)d_in[2];
    const float* W2        = (const float*)d_in[3];
    const float* b2        = (const float*)d_in[4];
    const float* gamma     = (const float*)d_in[5];
    const float* beta      = (const float*)d_in[6];
    const float* hgc1_bias = (const float*)d_in[7];
    const float* fc1_W     = (const float*)d_in[8];
    const float* fus_l1_W  = (const float*)d_in[9];
    const float* fus_l1_b  = (const float*)d_in[10];
    const float* fus_l2_W  = (const float*)d_in[11];
    const float* fus_l2_b  = (const float*)d_in[12];
    const float* hg_val    = (const float*)d_in[13];
    const int*   edge_index= (const int*)d_in[14];
    const int*   hg_row    = (const int*)d_in[15];
    const int*   hg_col    = (const int*)d_in[16];

    const int N    = in_sizes[0] / 64;
    const int E    = in_sizes[14] / 2;
    const int NNZ  = in_sizes[13];
    const int Np   = (N + 3) & ~3;
    const int NSEG = (N + 255) >> 8;
    const int* src = edge_index;
    const int* dst = edge_index + E;

    float* ws      = (float*)d_ws;
    float* dinv    = ws;
    float* sdi     = dinv + Np;
    float* w12     = sdi + Np;
    float* bw      = w12 + 4096;
    float* stats   = bw + 64;
    int*   gcn_off = (int*)(stats + 128);
    int*   hgc_off = gcn_off + (Np + 4);
    int*   hgr_off = hgc_off + (Np + 4);
    int*   segtot  = hgr_off + (Np + 4);
    int*   segoff  = segtot + 3 * NSEG;
    int*   blockcnt= segoff + 3 * NSEG;
    unsigned short* gcn_srcs = (unsigned short*)(blockcnt + 3 * NSEG * PBLK);
    unsigned* hgc_ent = (unsigned*)(gcn_srcs + ((E + 1) & ~1));
    unsigned* hgr_ent = hgc_ent + NNZ;
    float* buf1    = (float*)(hgr_ent + NNZ);
    float* buf2    = buf1 + (size_t)128 * Np;

    const int Ep = (E + 1) & ~1;
    unsigned* runG = (unsigned*)buf1;
    uint2*    runC = (uint2*)(runG + Ep);
    uint2*    runR = runC + NNZ;

    float* tbuf = buf2;                      // A-hat emb        N x 64
    float* ubuf = buf1;                      // A-hat^2 emb      N x 64
    float* h2   = buf1 + (size_t)64 * Np;    // raw h2 (pre-bn)  N x 64
    float* eemb = buf2;                      // edge emb         N x 64 (tbuf dead)
    float* x2   = buf1;                      // HGNN out         N x 64 (ubuf dead)
    float* out  = (float*)d_out;

    const float invN = 1.0f / (float)N;

    // --- CSR build: count -> scans -> scatter runs -> per-seg csr_build ---
    p1_count_kernel<<<PBLK, 256, 0, stream>>>(dst, E, hg_row, hg_col, NNZ, blockcnt, NSEG);
    p2a_kernel<<<(3 * NSEG + 3) / 4, 256, 0, stream>>>(blockcnt, segtot, 3 * NSEG);
    p2b_kernel<<<1, 192, 0, stream>>>(segtot, segoff, NSEG);
    p3_scatter_kernel<<<PBLK, 256, 0, stream>>>(src, dst, E, hg_row, hg_col, hg_val, NNZ,
                                                blockcnt, segoff, runG, runC, runR, NSEG);
    csr_build_kernel<<<NSEG, 256, 0, stream>>>(runG, runC, runR, segoff, segtot, NSEG, N,
                                               gcn_off, hgc_off, hgr_off, dinv,
                                               gcn_srcs, hgc_ent, hgr_ent);

    // --- weight precompute (also zeroes stats) + reassociated GCN ---
    wprep_kernel<<<65, 64, 0, stream>>>(W1, W2, b1, w12, bw, stats);
    gcn_gather_kernel<true><<<(N + 3) / 4, 256, 0, stream>>>(emb, dinv, gcn_off, gcn_srcs,
                                                             tbuf, sdi, N);
    gcn_gather_kernel<false><<<(N + 3) / 4, 256, 0, stream>>>(tbuf, dinv, gcn_off, gcn_srcs,
                                                              ubuf, nullptr, N);
    gemm_h2_kernel<<<(N + 63) / 64, 256, 0, stream>>>(ubuf, w12, bw, b2, sdi, h2, stats, N);

    // --- HGNN: edge_emb = G^T relu(bn(h2))+bias ; x2 = G edge_emb ---
    hg_gather_kernel<true><<<(N + 3) / 4, 256, 0, stream>>>(h2, hgc_off, hgc_ent,
                                                            stats, gamma, beta, hgc1_bias,
                                                            invN, eemb, N);
    hg_gather_kernel<false><<<(N + 3) / 4, 256, 0, stream>>>(eemb, hgr_off, hgr_ent,
                                                             nullptr, nullptr, nullptr, nullptr,
                                                             0.f, x2, N);

    // --- fused softmax + fc1 + fusion gate (bn on hidden inline) ---
    tail_kernel<<<(N + TROWS - 1) / TROWS, 256, 0, stream>>>(x2, h2, fc1_W, fus_l1_W, fus_l1_b,
                                                             fus_l2_W, fus_l2_b, stats, gamma, beta,
                                                             invN, out, N);
}